// Round 1
// baseline (462.036 us; speedup 1.0000x reference)
//
#include <hip/hip_runtime.h>
#include <cstddef>

// Mamba2 forward, fp32 correctness-first pipeline.
// Shapes: B=2 L=1024 DMODEL=768 DINNER=1536 NHEADS=192 P=8 N=64 CONVDIM=1664
// DINPROJ=3392, chunks: 8 x 128.
//
// ws layout (floats):
//   u      [2048][768]      transpose of x
//   zx     [2048][3392]     in-proj output (z | xBC_raw | dt_raw)
//   xBC    [2048][1664]     conv+silu output (xs | Bm | Cm)
//   dtb    [2][192][1024]   softplus dt, (b,h,t) layout
//   Acs    [2][192][8][128] per-chunk cumsum of dA
//   sc     [16][128][128]   chunk scores C.B^T
//   st     [16][192][8][64] per-chunk states
//   pv     [16][192][8][64] state entering each chunk
//   Yb     [2048][1536]     SSD output accum
//   y2     [2048][1536]     gated+normed
// total 22,413,312 floats = 89.7 MB

#define OFF_U   0
#define OFF_ZX  (OFF_U + 2048*768)
#define OFF_XBC (OFF_ZX + 2048*3392)
#define OFF_DT  (OFF_XBC + 2048*1664)
#define OFF_ACS (OFF_DT + 2*192*1024)
#define OFF_SC  (OFF_ACS + 2*192*8*128)
#define OFF_ST  (OFF_SC + 16*128*128)
#define OFF_PV  (OFF_ST + 16*192*512)
#define OFF_Y   (OFF_PV + 16*192*512)
#define OFF_Y2  (OFF_Y + 2048*1536)

__device__ __forceinline__ float siluf(float x) { return x / (1.f + __expf(-x)); }

// ---------- transpose x (B,768,1024) -> u (B*1024, 768) ----------
__global__ __launch_bounds__(256) void transpose_x_kernel(const float* __restrict__ x,
                                                          float* __restrict__ u) {
  __shared__ float tile[32][33];
  int b = blockIdx.z;
  int d0 = blockIdx.x * 32, l0 = blockIdx.y * 32;
  int tx = threadIdx.x & 31, ty = threadIdx.x >> 5;  // 32 x 8
  for (int r = ty; r < 32; r += 8)
    tile[r][tx] = x[((size_t)(b * 768 + d0 + r)) * 1024 + l0 + tx];
  __syncthreads();
  for (int r = ty; r < 32; r += 8)
    u[((size_t)(b * 1024 + l0 + r)) * 768 + d0 + tx] = tile[tx][r];
}

// ---------- C[M,N] = A[M,K] * B[N,K]^T, 128x64 tile, 8x4 micro ----------
template <bool TSTORE>
__global__ __launch_bounds__(256) void gemm_abt(const float* __restrict__ A,
                                                const float* __restrict__ B,
                                                float* __restrict__ C,
                                                int M, int N, int K) {
  __shared__ float As[16][132];
  __shared__ float Bs[16][68];
  int tid = threadIdx.x;
  int tx = tid & 15, ty = tid >> 4;
  int m0 = blockIdx.y * 128, n0 = blockIdx.x * 64;
  int la_m = tid >> 1;           // 0..127
  int la_k = (tid & 1) * 8;      // 0 or 8
  int lb_n = tid >> 2;           // 0..63
  int lb_k = (tid & 3) * 4;      // 0,4,8,12
  const float* Ap = A + (size_t)(m0 + la_m) * K + la_k;
  const float* Bp = B + (size_t)(n0 + lb_n) * K + lb_k;
  float acc[8][4] = {};
  for (int k0 = 0; k0 < K; k0 += 16) {
    float4 a0 = *(const float4*)(Ap + k0);
    float4 a1 = *(const float4*)(Ap + k0 + 4);
    float4 bv = *(const float4*)(Bp + k0);
    As[la_k + 0][la_m] = a0.x; As[la_k + 1][la_m] = a0.y;
    As[la_k + 2][la_m] = a0.z; As[la_k + 3][la_m] = a0.w;
    As[la_k + 4][la_m] = a1.x; As[la_k + 5][la_m] = a1.y;
    As[la_k + 6][la_m] = a1.z; As[la_k + 7][la_m] = a1.w;
    Bs[lb_k + 0][lb_n] = bv.x; Bs[lb_k + 1][lb_n] = bv.y;
    Bs[lb_k + 2][lb_n] = bv.z; Bs[lb_k + 3][lb_n] = bv.w;
    __syncthreads();
#pragma unroll
    for (int kk = 0; kk < 16; ++kk) {
      float4 a0r = *(const float4*)&As[kk][ty * 8];
      float4 a1r = *(const float4*)&As[kk][ty * 8 + 4];
      float4 br = *(const float4*)&Bs[kk][tx * 4];
      float am[8] = {a0r.x, a0r.y, a0r.z, a0r.w, a1r.x, a1r.y, a1r.z, a1r.w};
      float bn[4] = {br.x, br.y, br.z, br.w};
#pragma unroll
      for (int i = 0; i < 8; ++i)
#pragma unroll
        for (int j = 0; j < 4; ++j) acc[i][j] = fmaf(am[i], bn[j], acc[i][j]);
    }
    __syncthreads();
  }
#pragma unroll
  for (int i = 0; i < 8; ++i) {
    int m = m0 + ty * 8 + i;
    if (TSTORE) {
      int bb = m >> 10, lpos = m & 1023;
#pragma unroll
      for (int j = 0; j < 4; ++j)
        C[((size_t)(bb * 768 + n0 + tx * 4 + j)) * 1024 + lpos] = acc[i][j];
    } else {
      float4 v = make_float4(acc[i][0], acc[i][1], acc[i][2], acc[i][3]);
      *(float4*)&C[(size_t)m * N + n0 + tx * 4] = v;
    }
  }
}

// ---------- dt = softplus(zx[:, 3200+h] + dt_bias[h]) -> (b,h,t) ----------
__global__ __launch_bounds__(256) void dt_kernel(const float* __restrict__ zx,
                                                 const float* __restrict__ dt_bias,
                                                 float* __restrict__ dtb) {
  int i = blockIdx.x * 256 + threadIdx.x;  // over 2*192*1024
  int t = i & 1023;
  int bh = i >> 10;
  int h = bh % 192, b = bh / 192;
  float v = zx[((size_t)(b * 1024 + t)) * 3392 + 3200 + h] + dt_bias[h];
  dtb[i] = (v > 20.f) ? v : log1pf(__expf(v));
}

// ---------- depthwise causal conv + bias + silu ----------
__global__ __launch_bounds__(128) void conv_kernel(const float* __restrict__ zx,
                                                   const float* __restrict__ conv_w,
                                                   const float* __restrict__ conv_b,
                                                   float* __restrict__ xBC) {
  int ch = blockIdx.x * 128 + threadIdx.x;  // < 1664
  int m = blockIdx.y;                        // 0..2047
  int b = m >> 10, l = m & 1023;
  float acc = conv_b[ch];
#pragma unroll
  for (int j = 0; j < 4; ++j) {
    int tj = l - 3 + j;
    if (tj >= 0)
      acc = fmaf(conv_w[ch * 4 + j],
                 zx[((size_t)(b * 1024 + tj)) * 3392 + 1536 + ch], acc);
  }
  xBC[(size_t)m * 1664 + ch] = siluf(acc);
}

// ---------- per-chunk inclusive scan of dA ----------
__global__ __launch_bounds__(128) void scan_kernel(const float* __restrict__ dtb,
                                                   const float* __restrict__ A_log,
                                                   float* __restrict__ Acs) {
  __shared__ float s[128];
  int idx = blockIdx.x;  // (b*192+h)*8 + c
  int c = idx & 7;
  int bh = idx >> 3;
  int h = bh % 192, b = bh / 192;
  int l = threadIdx.x;
  float Ah = -__expf(A_log[h]);
  float v = dtb[(size_t)bh * 1024 + c * 128 + l] * Ah;
  (void)b;
  s[l] = v;
  __syncthreads();
  for (int off = 1; off < 128; off <<= 1) {
    float add = (l >= off) ? s[l - off] : 0.f;
    __syncthreads();
    s[l] += add;
    __syncthreads();
  }
  Acs[(size_t)idx * 128 + l] = s[l];
}

// ---------- scores[l,s] = sum_n Cm[l,n]*Bm[s,n], per (b,c) ----------
__global__ __launch_bounds__(256) void scores_kernel(const float* __restrict__ xBC,
                                                     float* __restrict__ scores) {
  __shared__ float Cs[16][128];
  __shared__ float Bs[16][128];
  int bc = blockIdx.x;
  const float* base = xBC + (size_t)bc * 128 * 1664;  // rows b*1024+c*128 == bc*128
  int tx = threadIdx.x & 15, ty = threadIdx.x >> 4;
  float acc[8][8] = {};
  for (int n0 = 0; n0 < 64; n0 += 16) {
    for (int id = threadIdx.x; id < 2048; id += 256) {
      int lr = id >> 4, nn = id & 15;
      Cs[nn][lr] = base[(size_t)lr * 1664 + 1600 + n0 + nn];
      Bs[nn][lr] = base[(size_t)lr * 1664 + 1536 + n0 + nn];
    }
    __syncthreads();
#pragma unroll
    for (int nn = 0; nn < 16; ++nn) {
      float a[8], bb[8];
#pragma unroll
      for (int i = 0; i < 8; ++i) {
        a[i] = Cs[nn][ty * 8 + i];
        bb[i] = Bs[nn][tx * 8 + i];
      }
#pragma unroll
      for (int i = 0; i < 8; ++i)
#pragma unroll
        for (int j = 0; j < 8; ++j) acc[i][j] = fmaf(a[i], bb[j], acc[i][j]);
    }
    __syncthreads();
  }
  float* srow = scores + (size_t)bc * 16384;
#pragma unroll
  for (int i = 0; i < 8; ++i)
#pragma unroll
    for (int j = 0; j < 8; ++j)
      srow[(size_t)(ty * 8 + i) * 128 + tx * 8 + j] = acc[i][j];
}

// ---------- Y_diag + chunk states, per (b,c,h) ----------
__global__ __launch_bounds__(128) void diag_states_kernel(
    const float* __restrict__ xBC, const float* __restrict__ dtb,
    const float* __restrict__ Acs, const float* __restrict__ scores,
    float* __restrict__ Y, float* __restrict__ states) {
  __shared__ float xdt_s[128][8];
  __shared__ float acs_s[128];
  __shared__ float decay_s[128];
  __shared__ float Bsh[128][64];
  __shared__ float sc_s[128][17];
  int idx = blockIdx.x;
  int h = idx % 192;
  int bc = idx / 192;
  int c = bc & 7, b = bc >> 3;
  int l = threadIdx.x;
  size_t rowt = (size_t)b * 1024 + c * 128 + l;
  float dtv = dtb[((size_t)(b * 192 + h)) * 1024 + c * 128 + l];
  float acs = Acs[(((size_t)(b * 192 + h)) * 8 + c) * 128 + l];
  acs_s[l] = acs;
  const float* xrow = xBC + rowt * 1664;
#pragma unroll
  for (int p = 0; p < 8; ++p) xdt_s[l][p] = xrow[h * 8 + p] * dtv;
  const float* Bbase = xBC + ((size_t)(b * 1024 + c * 128)) * 1664 + 1536;
  for (int id = l; id < 128 * 64; id += 128) {
    int r = id >> 6, col = id & 63;
    Bsh[r][col] = Bbase[(size_t)r * 1664 + col];
  }
  __syncthreads();
  float Asum = acs_s[127];
  decay_s[l] = __expf(Asum - acs);

  const float* sall = scores + (size_t)bc * 16384;
  float acc[8] = {0, 0, 0, 0, 0, 0, 0, 0};
  for (int s0 = 0; s0 < 128; s0 += 16) {
#pragma unroll
    for (int r = 0; r < 16; ++r) {
      int lin = l + r * 128;
      int lr = lin >> 4, sq = lin & 15;
      sc_s[lr][sq] = sall[(size_t)lr * 128 + s0 + sq];
    }
    __syncthreads();
    int send = (l < s0 + 15) ? l : (s0 + 15);
    for (int s = s0; s <= send; ++s) {
      float w = sc_s[l][s - s0] * __expf(acs - acs_s[s]);
#pragma unroll
      for (int p = 0; p < 8; ++p) acc[p] = fmaf(w, xdt_s[s][p], acc[p]);
    }
    __syncthreads();
  }
  float* yrow = Y + rowt * 1536 + h * 8;
#pragma unroll
  for (int p = 0; p < 8; ++p) yrow[p] = acc[p];

  // states: thread -> (p, n0..n0+3)
  int p = l >> 4, n0 = (l & 15) << 2;
  float st0 = 0, st1 = 0, st2 = 0, st3 = 0;
  for (int s = 0; s < 128; ++s) {
    float w2 = decay_s[s] * xdt_s[s][p];
    st0 = fmaf(w2, Bsh[s][n0 + 0], st0);
    st1 = fmaf(w2, Bsh[s][n0 + 1], st1);
    st2 = fmaf(w2, Bsh[s][n0 + 2], st2);
    st3 = fmaf(w2, Bsh[s][n0 + 3], st3);
  }
  float* sp = states + ((size_t)bc * 192 + h) * 512 + p * 64 + n0;
  sp[0] = st0; sp[1] = st1; sp[2] = st2; sp[3] = st3;
}

// ---------- inter-chunk recurrence, per (b,h) ----------
__global__ __launch_bounds__(512) void recur_kernel(const float* __restrict__ Acs,
                                                    const float* __restrict__ states,
                                                    float* __restrict__ prev) {
  int bh = blockIdx.x;
  int b = bh / 192, h = bh % 192;
  int tid = threadIdx.x;  // p*64+n
  float s_run = 0.f;
  for (int c = 0; c < 8; ++c) {
    size_t o = ((size_t)((b * 8 + c) * 192) + h) * 512 + tid;
    prev[o] = s_run;
    float dAs = Acs[(((size_t)(b * 192 + h)) * 8 + c) * 128 + 127];
    s_run = s_run * __expf(dAs) + states[o];
  }
}

// ---------- Y_off + D*xh, per (b,c,h) ----------
__global__ __launch_bounds__(128) void yoff_kernel(const float* __restrict__ xBC,
                                                   const float* __restrict__ Acs,
                                                   const float* __restrict__ prev,
                                                   const float* __restrict__ Dvec,
                                                   float* __restrict__ Y) {
  __shared__ float pv_s[512];
  int idx = blockIdx.x;
  int h = idx % 192;
  int bc = idx / 192;
  int c = bc & 7, b = bc >> 3;
  int l = threadIdx.x;
  const float* pb = prev + ((size_t)bc * 192 + h) * 512;
  for (int id = l; id < 512; id += 128) pv_s[id] = pb[id];
  __syncthreads();
  size_t rowt = (size_t)b * 1024 + c * 128 + l;
  float eacs = __expf(Acs[(((size_t)(b * 192 + h)) * 8 + c) * 128 + l]);
  const float* crow = xBC + rowt * 1664 + 1600;
  float acc[8] = {0, 0, 0, 0, 0, 0, 0, 0};
  for (int n = 0; n < 64; n += 4) {
    float4 cv = *(const float4*)&crow[n];
#pragma unroll
    for (int p = 0; p < 8; ++p) {
      acc[p] = fmaf(cv.x, pv_s[p * 64 + n + 0], acc[p]);
      acc[p] = fmaf(cv.y, pv_s[p * 64 + n + 1], acc[p]);
      acc[p] = fmaf(cv.z, pv_s[p * 64 + n + 2], acc[p]);
      acc[p] = fmaf(cv.w, pv_s[p * 64 + n + 3], acc[p]);
    }
  }
  float Dh = Dvec[h];
  const float* xrow = xBC + rowt * 1664 + h * 8;
  float* yrow = Y + rowt * 1536 + h * 8;
#pragma unroll
  for (int p = 0; p < 8; ++p) yrow[p] += acc[p] * eacs + Dh * xrow[p];
}

// ---------- gate with silu(z) + RMSNorm ----------
__global__ __launch_bounds__(256) void gatenorm_kernel(const float* __restrict__ Y,
                                                       const float* __restrict__ zx,
                                                       const float* __restrict__ norm_w,
                                                       float* __restrict__ y2) {
  int m = blockIdx.x;
  int tid = threadIdx.x;
  const float* yrow = Y + (size_t)m * 1536;
  const float* zrow = zx + (size_t)m * 3392;
  float vals[6];
  float ss = 0.f;
#pragma unroll
  for (int r = 0; r < 6; ++r) {
    int i = tid + r * 256;
    float v = yrow[i] * siluf(zrow[i]);
    vals[r] = v;
    ss = fmaf(v, v, ss);
  }
#pragma unroll
  for (int off = 32; off > 0; off >>= 1) ss += __shfl_down(ss, off);
  __shared__ float red[4];
  int lane = tid & 63, wid = tid >> 6;
  if (lane == 0) red[wid] = ss;
  __syncthreads();
  float tot = red[0] + red[1] + red[2] + red[3];
  float scale = rsqrtf(tot * (1.f / 1536.f) + 1e-5f);
#pragma unroll
  for (int r = 0; r < 6; ++r) {
    int i = tid + r * 256;
    y2[(size_t)m * 1536 + i] = vals[r] * scale * norm_w[i];
  }
}

extern "C" void kernel_launch(void* const* d_in, const int* in_sizes, int n_in,
                              void* d_out, int out_size, void* d_ws, size_t ws_size,
                              hipStream_t stream) {
  const float* x = (const float*)d_in[0];
  const float* W_in = (const float*)d_in[1];
  const float* conv_w = (const float*)d_in[2];
  const float* conv_b = (const float*)d_in[3];
  const float* dt_bias = (const float*)d_in[4];
  const float* A_log = (const float*)d_in[5];
  const float* Dvec = (const float*)d_in[6];
  const float* norm_w = (const float*)d_in[7];
  const float* W_out = (const float*)d_in[8];
  float* out = (float*)d_out;
  float* ws = (float*)d_ws;

  float* u = ws + OFF_U;
  float* zx = ws + OFF_ZX;
  float* xBC = ws + OFF_XBC;
  float* dtb = ws + OFF_DT;
  float* Acs = ws + OFF_ACS;
  float* sc = ws + OFF_SC;
  float* st = ws + OFF_ST;
  float* pv = ws + OFF_PV;
  float* Yb = ws + OFF_Y;
  float* y2 = ws + OFF_Y2;

  transpose_x_kernel<<<dim3(24, 32, 2), 256, 0, stream>>>(x, u);
  gemm_abt<false><<<dim3(53, 16), 256, 0, stream>>>(u, W_in, zx, 2048, 3392, 768);
  dt_kernel<<<1536, 256, 0, stream>>>(zx, dt_bias, dtb);
  conv_kernel<<<dim3(13, 2048), 128, 0, stream>>>(zx, conv_w, conv_b, xBC);
  scan_kernel<<<3072, 128, 0, stream>>>(dtb, A_log, Acs);
  scores_kernel<<<16, 256, 0, stream>>>(xBC, sc);
  diag_states_kernel<<<3072, 128, 0, stream>>>(xBC, dtb, Acs, sc, Yb, st);
  recur_kernel<<<384, 512, 0, stream>>>(Acs, st, pv);
  yoff_kernel<<<3072, 128, 0, stream>>>(xBC, Acs, pv, Dvec, Yb);
  gatenorm_kernel<<<2048, 256, 0, stream>>>(Yb, zx, norm_w, y2);
  gemm_abt<true><<<dim3(12, 16), 256, 0, stream>>>(y2, W_out, out, 2048, 768, 1536);
}

// Round 2
// 419.089 us; speedup vs baseline: 1.1025x; 1.1025x over previous
//
#include <hip/hip_runtime.h>
#include <cstddef>
#include <cstdint>

// Mamba2 forward. bf16 MFMA for the two big GEMMs, fp32 dt path.
// B=2 L=1024 DMODEL=768 DINNER=1536 NHEADS=192 P=8 N=64 CONVDIM=1664
// in-proj: zx[2048][3200] = u @ W_in[0:3200].T  (bf16 MFMA)
//          dtb            = softplus(u @ W_in[3200:].T + bias)  (fp32)
// out-proj: y3[2048][768] = y2b @ W_out.T (bf16 MFMA), then transpose.

typedef __bf16 bf16_t;
typedef bf16_t bf16x8 __attribute__((ext_vector_type(8)));
typedef float f32x4 __attribute__((ext_vector_type(4)));

// ---------------- ws layout (float units) ----------------
#define OFF_UB   ((size_t)0)                       // 2048*768 bf16
#define OFF_WBI  (OFF_UB  + 786432)                // 3200*768 bf16
#define OFF_WBO  (OFF_WBI + 1228800)               // 768*1536 bf16
#define OFF_ZX   (OFF_WBO + 589824)                // 2048*3200 f32
#define OFF_XBC  (OFF_ZX  + 6553600)               // 2048*1664 f32 (later aliased by y3 2048*768)
#define OFF_DT   (OFF_XBC + 3407872)               // 2*192*1024 f32
#define OFF_ACS  (OFF_DT  + 393216)                // 2*192*8*128 f32
#define OFF_SC   (OFF_ACS + 393216)                // 16*128*128 f32
#define OFF_ST   (OFF_SC  + 262144)                // 16*192*512 f32
#define OFF_PV   (OFF_ST  + 1572864)               // 16*192*512 f32
#define OFF_Y    (OFF_PV  + 1572864)               // 2048*1536 f32
#define OFF_Y2B  (OFF_Y   + 3145728)               // 2048*1536 bf16
// end = OFF_Y2B + 1572864 = 21,479,424 floats = 85.9 MB

__device__ __forceinline__ float siluf(float x) { return x / (1.f + __expf(-x)); }

// ---------- transpose x (B,768,1024) -> ub bf16 (B*1024, 768) ----------
__global__ __launch_bounds__(256) void transpose_x_kernel(const float* __restrict__ x,
                                                          bf16_t* __restrict__ ub) {
  __shared__ float tile[32][33];
  int b = blockIdx.z;
  int d0 = blockIdx.x * 32, l0 = blockIdx.y * 32;
  int tx = threadIdx.x & 31, ty = threadIdx.x >> 5;
  for (int r = ty; r < 32; r += 8)
    tile[r][tx] = x[((size_t)(b * 768 + d0 + r)) * 1024 + l0 + tx];
  __syncthreads();
  for (int r = ty; r < 32; r += 8)
    ub[((size_t)(b * 1024 + l0 + r)) * 768 + d0 + tx] = (bf16_t)tile[tx][r];
}

// ---------- fp32 -> bf16 bulk convert ----------
__global__ __launch_bounds__(256) void cvt_bf16_kernel(const float* __restrict__ src,
                                                       bf16_t* __restrict__ dst, int n) {
  int i = (blockIdx.x * 256 + threadIdx.x) * 4;
  if (i < n) {
    float4 v = *(const float4*)(src + i);
    dst[i + 0] = (bf16_t)v.x; dst[i + 1] = (bf16_t)v.y;
    dst[i + 2] = (bf16_t)v.z; dst[i + 3] = (bf16_t)v.w;
  }
}

// ---------- bf16 MFMA GEMM: C[M][ldc cols n0..] = A[M][K] * B[N][K]^T ----------
// 128x128 tile, BK=64, 4 waves (2x2), 4x4 16x16x32 frags per wave.
// LDS XOR-chunk swizzle: element (r,k) chunk c=k>>3 stored at chunk c^(r&7).
__global__ __launch_bounds__(256) void gemm_mfma_bt(const bf16_t* __restrict__ A,
                                                    const bf16_t* __restrict__ B,
                                                    float* __restrict__ C,
                                                    int K, int ldc) {
  __shared__ bf16_t Asmem[128 * 64];
  __shared__ bf16_t Bsmem[128 * 64];
  int tid = threadIdx.x;
  int wave = tid >> 6, lane = tid & 63;
  int wr = wave >> 1, wc = wave & 1;
  int m0 = blockIdx.y * 128, n0 = blockIdx.x * 128;
  const bf16_t* Ag = A + (size_t)m0 * K;
  const bf16_t* Bg = B + (size_t)n0 * K;

  int lofs[4];
  const bf16_t* agp[4];
  const bf16_t* bgp[4];
#pragma unroll
  for (int i = 0; i < 4; ++i) {
    int id = i * 256 + tid;
    int r = id >> 3, c = id & 7;
    lofs[i] = r * 128 + ((c ^ (r & 7)) << 4);
    agp[i] = Ag + (size_t)r * K + c * 8;
    bgp[i] = Bg + (size_t)r * K + c * 8;
  }

  f32x4 acc[4][4] = {};
  uint4 areg[4], breg[4];
#pragma unroll
  for (int i = 0; i < 4; ++i) {
    areg[i] = *(const uint4*)(agp[i]);
    breg[i] = *(const uint4*)(bgp[i]);
  }

  for (int k0 = 0; k0 < K; k0 += 64) {
    __syncthreads();
#pragma unroll
    for (int i = 0; i < 4; ++i) {
      *(uint4*)((char*)Asmem + lofs[i]) = areg[i];
      *(uint4*)((char*)Bsmem + lofs[i]) = breg[i];
    }
    __syncthreads();
    if (k0 + 64 < K) {
#pragma unroll
      for (int i = 0; i < 4; ++i) {
        areg[i] = *(const uint4*)(agp[i] + k0 + 64);
        breg[i] = *(const uint4*)(bgp[i] + k0 + 64);
      }
    }
#pragma unroll
    for (int half = 0; half < 2; ++half) {
      int kk = half * 32;
      bf16x8 af[4], bfr[4];
      int ca = (kk >> 3) + (lane >> 4);
      int swz = (ca ^ (lane & 7)) << 4;
#pragma unroll
      for (int f = 0; f < 4; ++f) {
        int Ra = wr * 64 + f * 16 + (lane & 15);
        int Rb = wc * 64 + f * 16 + (lane & 15);
        af[f] = *(const bf16x8*)((const char*)Asmem + Ra * 128 + swz);
        bfr[f] = *(const bf16x8*)((const char*)Bsmem + Rb * 128 + swz);
      }
#pragma unroll
      for (int i = 0; i < 4; ++i)
#pragma unroll
        for (int j = 0; j < 4; ++j)
          acc[i][j] = __builtin_amdgcn_mfma_f32_16x16x32_bf16(af[i], bfr[j], acc[i][j], 0, 0, 0);
    }
  }

  int colb = n0 + wc * 64 + (lane & 15);
  int rowb = m0 + wr * 64 + ((lane >> 4) << 2);
#pragma unroll
  for (int i = 0; i < 4; ++i)
#pragma unroll
    for (int j = 0; j < 4; ++j) {
      float* cp = C + (size_t)(rowb + i * 16) * ldc + colb + j * 16;
      cp[0] = acc[i][j][0];
      cp[(size_t)ldc] = acc[i][j][1];
      cp[(size_t)2 * ldc] = acc[i][j][2];
      cp[(size_t)3 * ldc] = acc[i][j][3];
    }
}

// ---------- fp32 dt projection + softplus: dtb[(b*192+h)*1024+l] ----------
// grid (192/32, 2048/64), 256 thr. Reads x directly (transpose via LDS).
__global__ __launch_bounds__(256) void dtproj_kernel(const float* __restrict__ x,
                                                     const float* __restrict__ W_in,
                                                     const float* __restrict__ dt_bias,
                                                     float* __restrict__ dtb) {
  __shared__ float As[16][65];   // [kk][m]
  __shared__ float Ws[32][17];   // [n][kk]
  int tid = threadIdx.x;
  int n0 = blockIdx.x * 32;
  int mm0 = blockIdx.y * 64;
  int b = mm0 >> 10, l0 = mm0 & 1023;
  int tx = tid & 31, ty = tid >> 5;
  float acc[8] = {};
  const float* Wbase = W_in + (size_t)(3200 + n0) * 768;
  const float* xbase = x + (size_t)b * 768 * 1024 + l0;
  for (int k0 = 0; k0 < 768; k0 += 16) {
    for (int i = tid; i < 1024; i += 256) {
      int kk = i >> 6, m = i & 63;
      As[kk][m] = xbase[(size_t)(k0 + kk) * 1024 + m];
    }
    for (int i = tid; i < 512; i += 256) {
      int n = i >> 4, kk = i & 15;
      Ws[n][kk] = Wbase[(size_t)n * 768 + k0 + kk];
    }
    __syncthreads();
#pragma unroll
    for (int kk = 0; kk < 16; ++kk) {
      float w = Ws[tx][kk];
#pragma unroll
      for (int r = 0; r < 8; ++r)
        acc[r] = fmaf(As[kk][ty + (r << 3)], w, acc[r]);
    }
    __syncthreads();
  }
  float bias = dt_bias[n0 + tx];
  size_t orow = ((size_t)(b * 192 + n0 + tx)) * 1024 + l0 + ty;
#pragma unroll
  for (int r = 0; r < 8; ++r) {
    float v = acc[r] + bias;
    dtb[orow + (r << 3)] = (v > 20.f) ? v : log1pf(__expf(v));
  }
}

// ---------- depthwise causal conv + bias + silu ----------
__global__ __launch_bounds__(128) void conv_kernel(const float* __restrict__ zx,
                                                   const float* __restrict__ conv_w,
                                                   const float* __restrict__ conv_b,
                                                   float* __restrict__ xBC) {
  int ch = blockIdx.x * 128 + threadIdx.x;
  int m = blockIdx.y;
  int b = m >> 10, l = m & 1023;
  float acc = conv_b[ch];
#pragma unroll
  for (int j = 0; j < 4; ++j) {
    int tj = l - 3 + j;
    if (tj >= 0)
      acc = fmaf(conv_w[ch * 4 + j],
                 zx[((size_t)(b * 1024 + tj)) * 3200 + 1536 + ch], acc);
  }
  xBC[(size_t)m * 1664 + ch] = siluf(acc);
}

// ---------- per-chunk inclusive scan of dA ----------
__global__ __launch_bounds__(128) void scan_kernel(const float* __restrict__ dtb,
                                                   const float* __restrict__ A_log,
                                                   float* __restrict__ Acs) {
  __shared__ float s[128];
  int idx = blockIdx.x;
  int c = idx & 7;
  int bh = idx >> 3;
  int h = bh % 192;
  int l = threadIdx.x;
  float Ah = -__expf(A_log[h]);
  float v = dtb[(size_t)bh * 1024 + c * 128 + l] * Ah;
  s[l] = v;
  __syncthreads();
  for (int off = 1; off < 128; off <<= 1) {
    float add = (l >= off) ? s[l - off] : 0.f;
    __syncthreads();
    s[l] += add;
    __syncthreads();
  }
  Acs[(size_t)idx * 128 + l] = s[l];
}

// ---------- scores[l,s] = sum_n Cm[l,n]*Bm[s,n], per (b,c) ----------
__global__ __launch_bounds__(256) void scores_kernel(const float* __restrict__ xBC,
                                                     float* __restrict__ scores) {
  __shared__ float Cs[16][128];
  __shared__ float Bs[16][128];
  int bc = blockIdx.x;
  const float* base = xBC + (size_t)bc * 128 * 1664;
  int tx = threadIdx.x & 15, ty = threadIdx.x >> 4;
  float acc[8][8] = {};
  for (int n0 = 0; n0 < 64; n0 += 16) {
    for (int id = threadIdx.x; id < 2048; id += 256) {
      int lr = id >> 4, nn = id & 15;
      Cs[nn][lr] = base[(size_t)lr * 1664 + 1600 + n0 + nn];
      Bs[nn][lr] = base[(size_t)lr * 1664 + 1536 + n0 + nn];
    }
    __syncthreads();
#pragma unroll
    for (int nn = 0; nn < 16; ++nn) {
      float a[8], bb[8];
#pragma unroll
      for (int i = 0; i < 8; ++i) {
        a[i] = Cs[nn][ty * 8 + i];
        bb[i] = Bs[nn][tx * 8 + i];
      }
#pragma unroll
      for (int i = 0; i < 8; ++i)
#pragma unroll
        for (int j = 0; j < 8; ++j) acc[i][j] = fmaf(a[i], bb[j], acc[i][j]);
    }
    __syncthreads();
  }
  float* srow = scores + (size_t)bc * 16384;
#pragma unroll
  for (int i = 0; i < 8; ++i)
#pragma unroll
    for (int j = 0; j < 8; ++j)
      srow[(size_t)(ty * 8 + i) * 128 + tx * 8 + j] = acc[i][j];
}

// ---------- Y_diag + chunk states, per (b,c,h) ----------
__global__ __launch_bounds__(128) void diag_states_kernel(
    const float* __restrict__ xBC, const float* __restrict__ dtb,
    const float* __restrict__ Acs, const float* __restrict__ scores,
    float* __restrict__ Y, float* __restrict__ states) {
  __shared__ float xdt_s[128][8];
  __shared__ float acs_s[128];
  __shared__ float decay_s[128];
  __shared__ float Bsh[128][64];
  __shared__ float sc_s[128][17];
  int idx = blockIdx.x;
  int h = idx % 192;
  int bc = idx / 192;
  int c = bc & 7, b = bc >> 3;
  int l = threadIdx.x;
  size_t rowt = (size_t)b * 1024 + c * 128 + l;
  float dtv = dtb[((size_t)(b * 192 + h)) * 1024 + c * 128 + l];
  float acs = Acs[(((size_t)(b * 192 + h)) * 8 + c) * 128 + l];
  acs_s[l] = acs;
  const float* xrow = xBC + rowt * 1664;
#pragma unroll
  for (int p = 0; p < 8; ++p) xdt_s[l][p] = xrow[h * 8 + p] * dtv;
  const float* Bbase = xBC + ((size_t)(b * 1024 + c * 128)) * 1664 + 1536;
  for (int id = l; id < 128 * 64; id += 128) {
    int r = id >> 6, col = id & 63;
    Bsh[r][col] = Bbase[(size_t)r * 1664 + col];
  }
  __syncthreads();
  float Asum = acs_s[127];
  decay_s[l] = __expf(Asum - acs);

  const float* sall = scores + (size_t)bc * 16384;
  float acc[8] = {0, 0, 0, 0, 0, 0, 0, 0};
  for (int s0 = 0; s0 < 128; s0 += 16) {
#pragma unroll
    for (int r = 0; r < 16; ++r) {
      int lin = l + r * 128;
      int lr = lin >> 4, sq = lin & 15;
      sc_s[lr][sq] = sall[(size_t)lr * 128 + s0 + sq];
    }
    __syncthreads();
    int send = (l < s0 + 15) ? l : (s0 + 15);
    for (int s = s0; s <= send; ++s) {
      float w = sc_s[l][s - s0] * __expf(acs - acs_s[s]);
#pragma unroll
      for (int p = 0; p < 8; ++p) acc[p] = fmaf(w, xdt_s[s][p], acc[p]);
    }
    __syncthreads();
  }
  float* yrow = Y + rowt * 1536 + h * 8;
#pragma unroll
  for (int p = 0; p < 8; ++p) yrow[p] = acc[p];

  int p = l >> 4, n0 = (l & 15) << 2;
  float st0 = 0, st1 = 0, st2 = 0, st3 = 0;
  for (int s = 0; s < 128; ++s) {
    float w2 = decay_s[s] * xdt_s[s][p];
    st0 = fmaf(w2, Bsh[s][n0 + 0], st0);
    st1 = fmaf(w2, Bsh[s][n0 + 1], st1);
    st2 = fmaf(w2, Bsh[s][n0 + 2], st2);
    st3 = fmaf(w2, Bsh[s][n0 + 3], st3);
  }
  float* sp = states + ((size_t)bc * 192 + h) * 512 + p * 64 + n0;
  sp[0] = st0; sp[1] = st1; sp[2] = st2; sp[3] = st3;
}

// ---------- inter-chunk recurrence, per (b,h) ----------
__global__ __launch_bounds__(512) void recur_kernel(const float* __restrict__ Acs,
                                                    const float* __restrict__ states,
                                                    float* __restrict__ prev) {
  int bh = blockIdx.x;
  int b = bh / 192, h = bh % 192;
  int tid = threadIdx.x;
  float s_run = 0.f;
  for (int c = 0; c < 8; ++c) {
    size_t o = ((size_t)((b * 8 + c) * 192) + h) * 512 + tid;
    prev[o] = s_run;
    float dAs = Acs[(((size_t)(b * 192 + h)) * 8 + c) * 128 + 127];
    s_run = s_run * __expf(dAs) + states[o];
  }
}

// ---------- Y_off + D*xh, per (b,c,h) ----------
__global__ __launch_bounds__(128) void yoff_kernel(const float* __restrict__ xBC,
                                                   const float* __restrict__ Acs,
                                                   const float* __restrict__ prev,
                                                   const float* __restrict__ Dvec,
                                                   float* __restrict__ Y) {
  __shared__ float pv_s[512];
  int idx = blockIdx.x;
  int h = idx % 192;
  int bc = idx / 192;
  int c = bc & 7, b = bc >> 3;
  int l = threadIdx.x;
  const float* pb = prev + ((size_t)bc * 192 + h) * 512;
  for (int id = l; id < 512; id += 128) pv_s[id] = pb[id];
  __syncthreads();
  size_t rowt = (size_t)b * 1024 + c * 128 + l;
  float eacs = __expf(Acs[(((size_t)(b * 192 + h)) * 8 + c) * 128 + l]);
  const float* crow = xBC + rowt * 1664 + 1600;
  float acc[8] = {0, 0, 0, 0, 0, 0, 0, 0};
  for (int n = 0; n < 64; n += 4) {
    float4 cv = *(const float4*)&crow[n];
#pragma unroll
    for (int p = 0; p < 8; ++p) {
      acc[p] = fmaf(cv.x, pv_s[p * 64 + n + 0], acc[p]);
      acc[p] = fmaf(cv.y, pv_s[p * 64 + n + 1], acc[p]);
      acc[p] = fmaf(cv.z, pv_s[p * 64 + n + 2], acc[p]);
      acc[p] = fmaf(cv.w, pv_s[p * 64 + n + 3], acc[p]);
    }
  }
  float Dh = Dvec[h];
  const float* xrow = xBC + rowt * 1664 + h * 8;
  float* yrow = Y + rowt * 1536 + h * 8;
#pragma unroll
  for (int p = 0; p < 8; ++p) yrow[p] += acc[p] * eacs + Dh * xrow[p];
}

// ---------- gate with silu(z) + RMSNorm -> y2 bf16 ----------
__global__ __launch_bounds__(256) void gatenorm_kernel(const float* __restrict__ Y,
                                                       const float* __restrict__ zx,
                                                       const float* __restrict__ norm_w,
                                                       bf16_t* __restrict__ y2b) {
  int m = blockIdx.x;
  int tid = threadIdx.x;
  const float* yrow = Y + (size_t)m * 1536;
  const float* zrow = zx + (size_t)m * 3200;
  float vals[6];
  float ss = 0.f;
#pragma unroll
  for (int r = 0; r < 6; ++r) {
    int i = tid + r * 256;
    float v = yrow[i] * siluf(zrow[i]);
    vals[r] = v;
    ss = fmaf(v, v, ss);
  }
#pragma unroll
  for (int off = 32; off > 0; off >>= 1) ss += __shfl_down(ss, off);
  __shared__ float red[4];
  int lane = tid & 63, wid = tid >> 6;
  if (lane == 0) red[wid] = ss;
  __syncthreads();
  float tot = red[0] + red[1] + red[2] + red[3];
  float scale = rsqrtf(tot * (1.f / 1536.f) + 1e-5f);
#pragma unroll
  for (int r = 0; r < 6; ++r) {
    int i = tid + r * 256;
    y2b[(size_t)m * 1536 + i] = (bf16_t)(vals[r] * scale * norm_w[i]);
  }
}

// ---------- transpose y3 (B*1024,768) -> out (B,768,1024) ----------
__global__ __launch_bounds__(256) void transpose_out_kernel(const float* __restrict__ y3,
                                                            float* __restrict__ out) {
  __shared__ float tile[32][33];
  int b = blockIdx.z;
  int d0 = blockIdx.x * 32, l0 = blockIdx.y * 32;
  int tx = threadIdx.x & 31, ty = threadIdx.x >> 5;
  for (int r = ty; r < 32; r += 8)
    tile[r][tx] = y3[((size_t)(b * 1024 + l0 + r)) * 768 + d0 + tx];
  __syncthreads();
  for (int r = ty; r < 32; r += 8)
    out[((size_t)(b * 768 + d0 + r)) * 1024 + l0 + tx] = tile[tx][r];
}

extern "C" void kernel_launch(void* const* d_in, const int* in_sizes, int n_in,
                              void* d_out, int out_size, void* d_ws, size_t ws_size,
                              hipStream_t stream) {
  const float* x = (const float*)d_in[0];
  const float* W_in = (const float*)d_in[1];
  const float* conv_w = (const float*)d_in[2];
  const float* conv_b = (const float*)d_in[3];
  const float* dt_bias = (const float*)d_in[4];
  const float* A_log = (const float*)d_in[5];
  const float* Dvec = (const float*)d_in[6];
  const float* norm_w = (const float*)d_in[7];
  const float* W_out = (const float*)d_in[8];
  float* out = (float*)d_out;
  float* ws = (float*)d_ws;

  bf16_t* ub = (bf16_t*)(ws + OFF_UB);
  bf16_t* Wbi = (bf16_t*)(ws + OFF_WBI);
  bf16_t* Wbo = (bf16_t*)(ws + OFF_WBO);
  float* zx = ws + OFF_ZX;
  float* xBC = ws + OFF_XBC;
  float* y3 = ws + OFF_XBC;  // alias: xBC dead before out-proj
  float* dtb = ws + OFF_DT;
  float* Acs = ws + OFF_ACS;
  float* sc = ws + OFF_SC;
  float* st = ws + OFF_ST;
  float* pv = ws + OFF_PV;
  float* Yb = ws + OFF_Y;
  bf16_t* y2b = (bf16_t*)(ws + OFF_Y2B);

  transpose_x_kernel<<<dim3(24, 32, 2), 256, 0, stream>>>(x, ub);
  cvt_bf16_kernel<<<2400, 256, 0, stream>>>(W_in, Wbi, 3200 * 768);
  cvt_bf16_kernel<<<1152, 256, 0, stream>>>(W_out, Wbo, 768 * 1536);
  gemm_mfma_bt<<<dim3(25, 16), 256, 0, stream>>>(ub, Wbi, zx, 768, 3200);
  dtproj_kernel<<<dim3(6, 32), 256, 0, stream>>>(x, W_in, dt_bias, dtb);
  conv_kernel<<<dim3(13, 2048), 128, 0, stream>>>(zx, conv_w, conv_b, xBC);
  scan_kernel<<<3072, 128, 0, stream>>>(dtb, A_log, Acs);
  scores_kernel<<<16, 256, 0, stream>>>(xBC, sc);
  diag_states_kernel<<<3072, 128, 0, stream>>>(xBC, dtb, Acs, sc, Yb, st);
  recur_kernel<<<384, 512, 0, stream>>>(Acs, st, pv);
  yoff_kernel<<<3072, 128, 0, stream>>>(xBC, Acs, pv, Dvec, Yb);
  gatenorm_kernel<<<2048, 256, 0, stream>>>(Yb, zx, norm_w, y2b);
  gemm_mfma_bt<<<dim3(6, 16), 256, 0, stream>>>(y2b, Wbo, y3, 1536, 768);
  transpose_out_kernel<<<dim3(24, 32, 2), 256, 0, stream>>>(y3, out);
}

// Round 3
// 327.902 us; speedup vs baseline: 1.4091x; 1.2781x over previous
//
#include <hip/hip_runtime.h>
#include <cstddef>
#include <cstdint>

// Mamba2 forward. bf16 MFMA GEMMs (LDS-staged coalesced epilogue), fp32 dt path.
// B=2 L=1024 DMODEL=768 DINNER=1536 NHEADS=192 P=8 N=64 CONVDIM=1664

typedef __bf16 bf16_t;
typedef bf16_t bf16x8 __attribute__((ext_vector_type(8)));
typedef float f32x4 __attribute__((ext_vector_type(4)));

// ---------------- ws layout (float units) ----------------
#define OFF_UB   ((size_t)0)                       // 2048*768 bf16
#define OFF_WBI  (OFF_UB  + 786432)                // 3200*768 bf16
#define OFF_WBO  (OFF_WBI + 1228800)               // 768*1536 bf16
#define OFF_ZX   (OFF_WBO + 589824)                // 2048*3200 f32
#define OFF_XBC  (OFF_ZX  + 6553600)               // 2048*1664 f32 (later aliased by y3)
#define OFF_DT   (OFF_XBC + 3407872)               // 2*192*1024 f32
#define OFF_ACS  (OFF_DT  + 393216)                // 2*192*8*128 f32
#define OFF_SC   (OFF_ACS + 393216)                // 16*128*128 f32
#define OFF_ST   (OFF_SC  + 262144)                // 16*192*512 f32
#define OFF_PV   (OFF_ST  + 1572864)               // 16*192*512 f32
#define OFF_Y    (OFF_PV  + 1572864)               // 2048*1536 f32
#define OFF_Y2B  (OFF_Y   + 3145728)               // 2048*1536 bf16

__device__ __forceinline__ float siluf(float x) { return x / (1.f + __expf(-x)); }

// ---------- transpose x (B,768,1024) -> ub bf16 (B*1024, 768) ----------
__global__ __launch_bounds__(256) void transpose_x_kernel(const float* __restrict__ x,
                                                          bf16_t* __restrict__ ub) {
  __shared__ float tile[32][33];
  int b = blockIdx.z;
  int d0 = blockIdx.x * 32, l0 = blockIdx.y * 32;
  int tx = threadIdx.x & 31, ty = threadIdx.x >> 5;
  for (int r = ty; r < 32; r += 8)
    tile[r][tx] = x[((size_t)(b * 768 + d0 + r)) * 1024 + l0 + tx];
  __syncthreads();
  for (int r = ty; r < 32; r += 8)
    ub[((size_t)(b * 1024 + l0 + r)) * 768 + d0 + tx] = (bf16_t)tile[tx][r];
}

// ---------- fp32 -> bf16 bulk convert ----------
__global__ __launch_bounds__(256) void cvt_bf16_kernel(const float* __restrict__ src,
                                                       bf16_t* __restrict__ dst, int n) {
  int i = (blockIdx.x * 256 + threadIdx.x) * 4;
  if (i < n) {
    float4 v = *(const float4*)(src + i);
    dst[i + 0] = (bf16_t)v.x; dst[i + 1] = (bf16_t)v.y;
    dst[i + 2] = (bf16_t)v.z; dst[i + 3] = (bf16_t)v.w;
  }
}

// ---------- bf16 MFMA GEMM: C[M][ldc @ n0..] = A[M][K] * B[N][K]^T ----------
// Tile: (TMF*32) rows x 128 cols, BK=64, 4 waves (2 row x 2 col),
// TMF x 4 16x16x32 frags per wave. XOR-chunk LDS swizzle (store & read same
// involution). Epilogue: LDS-staged [64][132] f32 -> coalesced float4 stores.
// XCD-bijective block swizzle (grid count % 8 == 0).
template <int TMF>
__global__ __launch_bounds__(256) void gemm_mfma_bt(const bf16_t* __restrict__ A,
                                                    const bf16_t* __restrict__ B,
                                                    float* __restrict__ C,
                                                    int K, int ldc) {
  constexpr int RB = TMF * 32;   // block rows
  constexpr int NA = RB / 32;    // A-tile loads per thread
  __shared__ __align__(16) float smemf[8448];  // 33792 B: staging union epilogue
  bf16_t* Asmem = (bf16_t*)smemf;
  bf16_t* Bsmem = Asmem + RB * 64;
  float* eps = smemf;

  int tid = threadIdx.x;
  int wave = tid >> 6, lane = tid & 63;
  int wr = wave >> 1, wc = wave & 1;

  // XCD-aware bijective swizzle
  int nwg = gridDim.x * gridDim.y;
  int flat = blockIdx.y * gridDim.x + blockIdx.x;
  int q = nwg >> 3;
  int swz = (flat & 7) * q + (flat >> 3);
  int bx = swz % gridDim.x, by = swz / gridDim.x;
  int m0 = by * RB, n0 = bx * 128;

  const bf16_t* Ag = A + (size_t)m0 * K;
  const bf16_t* Bg = B + (size_t)n0 * K;

  int aofs[NA]; const bf16_t* agp[NA];
#pragma unroll
  for (int i = 0; i < NA; ++i) {
    int id = i * 256 + tid;
    int r = id >> 3, c = id & 7;
    aofs[i] = r * 128 + ((c ^ (r & 7)) << 4);
    agp[i] = Ag + (size_t)r * K + c * 8;
  }
  int bofs[4]; const bf16_t* bgp[4];
#pragma unroll
  for (int i = 0; i < 4; ++i) {
    int id = i * 256 + tid;
    int r = id >> 3, c = id & 7;
    bofs[i] = r * 128 + ((c ^ (r & 7)) << 4);
    bgp[i] = Bg + (size_t)r * K + c * 8;
  }

  f32x4 acc[TMF][4] = {};
  uint4 areg[NA], breg[4];
#pragma unroll
  for (int i = 0; i < NA; ++i) areg[i] = *(const uint4*)(agp[i]);
#pragma unroll
  for (int i = 0; i < 4; ++i) breg[i] = *(const uint4*)(bgp[i]);

  for (int k0 = 0; k0 < K; k0 += 64) {
    __syncthreads();
#pragma unroll
    for (int i = 0; i < NA; ++i) *(uint4*)((char*)Asmem + aofs[i]) = areg[i];
#pragma unroll
    for (int i = 0; i < 4; ++i) *(uint4*)((char*)Bsmem + bofs[i]) = breg[i];
    __syncthreads();
    if (k0 + 64 < K) {
#pragma unroll
      for (int i = 0; i < NA; ++i) areg[i] = *(const uint4*)(agp[i] + k0 + 64);
#pragma unroll
      for (int i = 0; i < 4; ++i) breg[i] = *(const uint4*)(bgp[i] + k0 + 64);
    }
#pragma unroll
    for (int half = 0; half < 2; ++half) {
      int kk = half * 32;
      int ca = (kk >> 3) + (lane >> 4);
      bf16x8 af[TMF], bfr[4];
#pragma unroll
      for (int f = 0; f < TMF; ++f) {
        int Ra = wr * (TMF * 16) + f * 16 + (lane & 15);
        af[f] = *(const bf16x8*)((const char*)Asmem + Ra * 128 + ((ca ^ (Ra & 7)) << 4));
      }
#pragma unroll
      for (int f = 0; f < 4; ++f) {
        int Rb = wc * 64 + f * 16 + (lane & 15);
        bfr[f] = *(const bf16x8*)((const char*)Bsmem + Rb * 128 + ((ca ^ (Rb & 7)) << 4));
      }
#pragma unroll
      for (int i = 0; i < TMF; ++i)
#pragma unroll
        for (int j = 0; j < 4; ++j)
          acc[i][j] = __builtin_amdgcn_mfma_f32_16x16x32_bf16(af[i], bfr[j], acc[i][j], 0, 0, 0);
    }
  }

  // Epilogue: stage 64-row slabs in LDS, store coalesced float4.
#pragma unroll
  for (int p = 0; p < RB / 64; ++p) {
    __syncthreads();
#pragma unroll
    for (int i = 0; i < TMF; ++i) {
      int rg = wr * (TMF * 16) + i * 16;
      if ((rg >> 6) == p) {
        int rl = (rg & 63) + ((lane >> 4) << 2);
#pragma unroll
        for (int j = 0; j < 4; ++j) {
          int col = wc * 64 + j * 16 + (lane & 15);
#pragma unroll
          for (int rr = 0; rr < 4; ++rr)
            eps[(rl + rr) * 132 + col] = acc[i][j][rr];
        }
      }
    }
    __syncthreads();
#pragma unroll
    for (int r = 0; r < 8; ++r) {
      int idx = tid + r * 256;
      int row = idx >> 5, c4 = (idx & 31) << 2;
      float4 v = *(const float4*)&eps[row * 132 + c4];
      *(float4*)&C[(size_t)(m0 + p * 64 + row) * ldc + n0 + c4] = v;
    }
  }
}

// ---------- fp32 dt projection + softplus -> dtb[(b*192+h)*1024+t] ----------
// grid (8 t-tiles, 24 h-tiles, 2 b), 256 thr. out tile: 8 h x 128 t.
__global__ __launch_bounds__(256) void dtproj_kernel(const float* __restrict__ x,
                                                     const float* __restrict__ W_in,
                                                     const float* __restrict__ dt_bias,
                                                     float* __restrict__ dtb) {
  __shared__ float xs[32][128];
  __shared__ float wsm[8][32];
  int tid = threadIdx.x;
  int t0 = blockIdx.x * 128;
  int h0 = blockIdx.y * 8;
  int b = blockIdx.z;
  int t = tid & 127;
  int hh = tid >> 7;  // 0/1
  float acc[4] = {};
  const float* xb = x + (size_t)b * 768 * 1024 + t0;
  const float* wb = W_in + (size_t)(3200 + h0) * 768;
  for (int k0 = 0; k0 < 768; k0 += 32) {
#pragma unroll
    for (int r2 = 0; r2 < 4; ++r2) {
      int idx = tid + r2 * 256;
      int kk = idx >> 5, c4 = (idx & 31) << 2;
      *(float4*)&xs[kk][c4] = *(const float4*)&xb[(size_t)(k0 + kk) * 1024 + c4];
    }
    {
      int h = tid >> 5, kk = tid & 31;
      wsm[h][kk] = wb[(size_t)h * 768 + k0 + kk];
    }
    __syncthreads();
#pragma unroll
    for (int kk = 0; kk < 32; ++kk) {
      float xv = xs[kk][t];
#pragma unroll
      for (int j = 0; j < 4; ++j)
        acc[j] = fmaf(xv, wsm[hh * 4 + j][kk], acc[j]);
    }
    __syncthreads();
  }
#pragma unroll
  for (int j = 0; j < 4; ++j) {
    int h = h0 + hh * 4 + j;
    float v = acc[j] + dt_bias[h];
    dtb[((size_t)(b * 192 + h)) * 1024 + t0 + t] = (v > 20.f) ? v : log1pf(__expf(v));
  }
}

// ---------- depthwise causal conv + bias + silu ----------
__global__ __launch_bounds__(128) void conv_kernel(const float* __restrict__ zx,
                                                   const float* __restrict__ conv_w,
                                                   const float* __restrict__ conv_b,
                                                   float* __restrict__ xBC) {
  int ch = blockIdx.x * 128 + threadIdx.x;
  int m = blockIdx.y;
  int b = m >> 10, l = m & 1023;
  float acc = conv_b[ch];
#pragma unroll
  for (int j = 0; j < 4; ++j) {
    int tj = l - 3 + j;
    if (tj >= 0)
      acc = fmaf(conv_w[ch * 4 + j],
                 zx[((size_t)(b * 1024 + tj)) * 3200 + 1536 + ch], acc);
  }
  xBC[(size_t)m * 1664 + ch] = siluf(acc);
}

// ---------- per-chunk inclusive scan of dA ----------
__global__ __launch_bounds__(128) void scan_kernel(const float* __restrict__ dtb,
                                                   const float* __restrict__ A_log,
                                                   float* __restrict__ Acs) {
  __shared__ float s[128];
  int idx = blockIdx.x;
  int c = idx & 7;
  int bh = idx >> 3;
  int h = bh % 192;
  int l = threadIdx.x;
  float Ah = -__expf(A_log[h]);
  float v = dtb[(size_t)bh * 1024 + c * 128 + l] * Ah;
  s[l] = v;
  __syncthreads();
  for (int off = 1; off < 128; off <<= 1) {
    float add = (l >= off) ? s[l - off] : 0.f;
    __syncthreads();
    s[l] += add;
    __syncthreads();
  }
  Acs[(size_t)idx * 128 + l] = s[l];
}

// ---------- scores[l,s] = sum_n Cm[l,n]*Bm[s,n], per (b,c) ----------
__global__ __launch_bounds__(256) void scores_kernel(const float* __restrict__ xBC,
                                                     float* __restrict__ scores) {
  __shared__ float Cs[16][128];
  __shared__ float Bs[16][128];
  int bc = blockIdx.x;
  const float* base = xBC + (size_t)bc * 128 * 1664;
  int tx = threadIdx.x & 15, ty = threadIdx.x >> 4;
  float acc[8][8] = {};
  for (int n0 = 0; n0 < 64; n0 += 16) {
    for (int id = threadIdx.x; id < 2048; id += 256) {
      int lr = id >> 4, nn = id & 15;
      Cs[nn][lr] = base[(size_t)lr * 1664 + 1600 + n0 + nn];
      Bs[nn][lr] = base[(size_t)lr * 1664 + 1536 + n0 + nn];
    }
    __syncthreads();
#pragma unroll
    for (int nn = 0; nn < 16; ++nn) {
      float a[8], bb[8];
#pragma unroll
      for (int i = 0; i < 8; ++i) {
        a[i] = Cs[nn][ty * 8 + i];
        bb[i] = Bs[nn][tx * 8 + i];
      }
#pragma unroll
      for (int i = 0; i < 8; ++i)
#pragma unroll
        for (int j = 0; j < 8; ++j) acc[i][j] = fmaf(a[i], bb[j], acc[i][j]);
    }
    __syncthreads();
  }
  float* srow = scores + (size_t)bc * 16384;
#pragma unroll
  for (int i = 0; i < 8; ++i)
#pragma unroll
    for (int j = 0; j < 8; ++j)
      srow[(size_t)(ty * 8 + i) * 128 + tx * 8 + j] = acc[i][j];
}

// ---------- Y_diag + chunk states, per (b,c,h) ----------
__global__ __launch_bounds__(128) void diag_states_kernel(
    const float* __restrict__ xBC, const float* __restrict__ dtb,
    const float* __restrict__ Acs, const float* __restrict__ scores,
    float* __restrict__ Y, float* __restrict__ states) {
  __shared__ float xdt_s[128][8];
  __shared__ float acs_s[128];
  __shared__ float decay_s[128];
  __shared__ float Bsh[128][64];
  __shared__ float sc_s[128][17];
  int idx = blockIdx.x;
  int h = idx % 192;
  int bc = idx / 192;
  int c = bc & 7, b = bc >> 3;
  int l = threadIdx.x;
  size_t rowt = (size_t)b * 1024 + c * 128 + l;
  float dtv = dtb[((size_t)(b * 192 + h)) * 1024 + c * 128 + l];
  float acs = Acs[(((size_t)(b * 192 + h)) * 8 + c) * 128 + l];
  acs_s[l] = acs;
  const float* xrow = xBC + rowt * 1664;
#pragma unroll
  for (int p = 0; p < 8; ++p) xdt_s[l][p] = xrow[h * 8 + p] * dtv;
  const float* Bbase = xBC + ((size_t)(b * 1024 + c * 128)) * 1664 + 1536;
  for (int id = l; id < 128 * 64; id += 128) {
    int r = id >> 6, col = id & 63;
    Bsh[r][col] = Bbase[(size_t)r * 1664 + col];
  }
  __syncthreads();
  float Asum = acs_s[127];
  decay_s[l] = __expf(Asum - acs);

  const float* sall = scores + (size_t)bc * 16384;
  float acc[8] = {0, 0, 0, 0, 0, 0, 0, 0};
  for (int s0 = 0; s0 < 128; s0 += 16) {
#pragma unroll
    for (int r = 0; r < 16; ++r) {
      int lin = l + r * 128;
      int lr = lin >> 4, sq = lin & 15;
      sc_s[lr][sq] = sall[(size_t)lr * 128 + s0 + sq];
    }
    __syncthreads();
    int send = (l < s0 + 15) ? l : (s0 + 15);
    for (int s = s0; s <= send; ++s) {
      float w = sc_s[l][s - s0] * __expf(acs - acs_s[s]);
#pragma unroll
      for (int p = 0; p < 8; ++p) acc[p] = fmaf(w, xdt_s[s][p], acc[p]);
    }
    __syncthreads();
  }
  float* yrow = Y + rowt * 1536 + h * 8;
#pragma unroll
  for (int p = 0; p < 8; ++p) yrow[p] = acc[p];

  int p = l >> 4, n0 = (l & 15) << 2;
  float st0 = 0, st1 = 0, st2 = 0, st3 = 0;
  for (int s = 0; s < 128; ++s) {
    float w2 = decay_s[s] * xdt_s[s][p];
    st0 = fmaf(w2, Bsh[s][n0 + 0], st0);
    st1 = fmaf(w2, Bsh[s][n0 + 1], st1);
    st2 = fmaf(w2, Bsh[s][n0 + 2], st2);
    st3 = fmaf(w2, Bsh[s][n0 + 3], st3);
  }
  float* sp = states + ((size_t)bc * 192 + h) * 512 + p * 64 + n0;
  sp[0] = st0; sp[1] = st1; sp[2] = st2; sp[3] = st3;
}

// ---------- inter-chunk recurrence, per (b,h) ----------
__global__ __launch_bounds__(512) void recur_kernel(const float* __restrict__ Acs,
                                                    const float* __restrict__ states,
                                                    float* __restrict__ prev) {
  int bh = blockIdx.x;
  int b = bh / 192, h = bh % 192;
  int tid = threadIdx.x;
  float s_run = 0.f;
  for (int c = 0; c < 8; ++c) {
    size_t o = ((size_t)((b * 8 + c) * 192) + h) * 512 + tid;
    prev[o] = s_run;
    float dAs = Acs[(((size_t)(b * 192 + h)) * 8 + c) * 128 + 127];
    s_run = s_run * __expf(dAs) + states[o];
  }
}

// ---------- Y_off + D*xh, per (b,c,h) ----------
__global__ __launch_bounds__(128) void yoff_kernel(const float* __restrict__ xBC,
                                                   const float* __restrict__ Acs,
                                                   const float* __restrict__ prev,
                                                   const float* __restrict__ Dvec,
                                                   float* __restrict__ Y) {
  __shared__ float pv_s[512];
  int idx = blockIdx.x;
  int h = idx % 192;
  int bc = idx / 192;
  int c = bc & 7, b = bc >> 3;
  int l = threadIdx.x;
  const float* pb = prev + ((size_t)bc * 192 + h) * 512;
  for (int id = l; id < 512; id += 128) pv_s[id] = pb[id];
  __syncthreads();
  size_t rowt = (size_t)b * 1024 + c * 128 + l;
  float eacs = __expf(Acs[(((size_t)(b * 192 + h)) * 8 + c) * 128 + l]);
  const float* crow = xBC + rowt * 1664 + 1600;
  float acc[8] = {0, 0, 0, 0, 0, 0, 0, 0};
  for (int n = 0; n < 64; n += 4) {
    float4 cv = *(const float4*)&crow[n];
#pragma unroll
    for (int p = 0; p < 8; ++p) {
      acc[p] = fmaf(cv.x, pv_s[p * 64 + n + 0], acc[p]);
      acc[p] = fmaf(cv.y, pv_s[p * 64 + n + 1], acc[p]);
      acc[p] = fmaf(cv.z, pv_s[p * 64 + n + 2], acc[p]);
      acc[p] = fmaf(cv.w, pv_s[p * 64 + n + 3], acc[p]);
    }
  }
  float Dh = Dvec[h];
  const float* xrow = xBC + rowt * 1664 + h * 8;
  float* yrow = Y + rowt * 1536 + h * 8;
#pragma unroll
  for (int p = 0; p < 8; ++p) yrow[p] += acc[p] * eacs + Dh * xrow[p];
}

// ---------- gate with silu(z) + RMSNorm -> y2 bf16 ----------
__global__ __launch_bounds__(256) void gatenorm_kernel(const float* __restrict__ Y,
                                                       const float* __restrict__ zx,
                                                       const float* __restrict__ norm_w,
                                                       bf16_t* __restrict__ y2b) {
  int m = blockIdx.x;
  int tid = threadIdx.x;
  const float* yrow = Y + (size_t)m * 1536;
  const float* zrow = zx + (size_t)m * 3200;
  float vals[6];
  float ss = 0.f;
#pragma unroll
  for (int r = 0; r < 6; ++r) {
    int i = tid + r * 256;
    float v = yrow[i] * siluf(zrow[i]);
    vals[r] = v;
    ss = fmaf(v, v, ss);
  }
#pragma unroll
  for (int off = 32; off > 0; off >>= 1) ss += __shfl_down(ss, off);
  __shared__ float red[4];
  int lane = tid & 63, wid = tid >> 6;
  if (lane == 0) red[wid] = ss;
  __syncthreads();
  float tot = red[0] + red[1] + red[2] + red[3];
  float scale = rsqrtf(tot * (1.f / 1536.f) + 1e-5f);
#pragma unroll
  for (int r = 0; r < 6; ++r) {
    int i = tid + r * 256;
    y2b[(size_t)m * 1536 + i] = (bf16_t)(vals[r] * scale * norm_w[i]);
  }
}

// ---------- transpose y3 (B*1024,768) -> out (B,768,1024) ----------
__global__ __launch_bounds__(256) void transpose_out_kernel(const float* __restrict__ y3,
                                                            float* __restrict__ out) {
  __shared__ float tile[32][33];
  int b = blockIdx.z;
  int d0 = blockIdx.x * 32, l0 = blockIdx.y * 32;
  int tx = threadIdx.x & 31, ty = threadIdx.x >> 5;
  for (int r = ty; r < 32; r += 8)
    tile[r][tx] = y3[((size_t)(b * 1024 + l0 + r)) * 768 + d0 + tx];
  __syncthreads();
  for (int r = ty; r < 32; r += 8)
    out[((size_t)(b * 768 + d0 + r)) * 1024 + l0 + tx] = tile[tx][r];
}

extern "C" void kernel_launch(void* const* d_in, const int* in_sizes, int n_in,
                              void* d_out, int out_size, void* d_ws, size_t ws_size,
                              hipStream_t stream) {
  const float* x = (const float*)d_in[0];
  const float* W_in = (const float*)d_in[1];
  const float* conv_w = (const float*)d_in[2];
  const float* conv_b = (const float*)d_in[3];
  const float* dt_bias = (const float*)d_in[4];
  const float* A_log = (const float*)d_in[5];
  const float* Dvec = (const float*)d_in[6];
  const float* norm_w = (const float*)d_in[7];
  const float* W_out = (const float*)d_in[8];
  float* out = (float*)d_out;
  float* ws = (float*)d_ws;

  bf16_t* ub = (bf16_t*)(ws + OFF_UB);
  bf16_t* Wbi = (bf16_t*)(ws + OFF_WBI);
  bf16_t* Wbo = (bf16_t*)(ws + OFF_WBO);
  float* zx = ws + OFF_ZX;
  float* xBC = ws + OFF_XBC;
  float* y3 = ws + OFF_XBC;  // alias: xBC dead before out-proj
  float* dtb = ws + OFF_DT;
  float* Acs = ws + OFF_ACS;
  float* sc = ws + OFF_SC;
  float* st = ws + OFF_ST;
  float* pv = ws + OFF_PV;
  float* Yb = ws + OFF_Y;
  bf16_t* y2b = (bf16_t*)(ws + OFF_Y2B);

  transpose_x_kernel<<<dim3(24, 32, 2), 256, 0, stream>>>(x, ub);
  cvt_bf16_kernel<<<2400, 256, 0, stream>>>(W_in, Wbi, 3200 * 768);
  cvt_bf16_kernel<<<1152, 256, 0, stream>>>(W_out, Wbo, 768 * 1536);
  gemm_mfma_bt<4><<<dim3(25, 16), 256, 0, stream>>>(ub, Wbi, zx, 768, 3200);
  dtproj_kernel<<<dim3(8, 24, 2), 256, 0, stream>>>(x, W_in, dt_bias, dtb);
  conv_kernel<<<dim3(13, 2048), 128, 0, stream>>>(zx, conv_w, conv_b, xBC);
  scan_kernel<<<3072, 128, 0, stream>>>(dtb, A_log, Acs);
  scores_kernel<<<16, 256, 0, stream>>>(xBC, sc);
  diag_states_kernel<<<3072, 128, 0, stream>>>(xBC, dtb, Acs, sc, Yb, st);
  recur_kernel<<<384, 512, 0, stream>>>(Acs, st, pv);
  yoff_kernel<<<3072, 128, 0, stream>>>(xBC, Acs, pv, Dvec, Yb);
  gatenorm_kernel<<<2048, 256, 0, stream>>>(Yb, zx, norm_w, y2b);
  gemm_mfma_bt<2><<<dim3(6, 32), 256, 0, stream>>>(y2b, Wbo, y3, 1536, 768);
  transpose_out_kernel<<<dim3(24, 32, 2), 256, 0, stream>>>(y3, out);
}

// Round 4
// 281.374 us; speedup vs baseline: 1.6421x; 1.1654x over previous
//
#include <hip/hip_runtime.h>
#include <cstddef>
#include <cstdint>

// Mamba2 forward. bf16 MFMA for: in/out-proj GEMMs, Y_diag, chunk-states.
// B=2 L=1024 DMODEL=768 DINNER=1536 NHEADS=192 P=8 N=64 CONVDIM=1664

typedef __bf16 bf16_t;
typedef bf16_t bf16x8 __attribute__((ext_vector_type(8)));
typedef float f32x4 __attribute__((ext_vector_type(4)));

// ---------------- ws layout (float units) ----------------
#define OFF_UB   ((size_t)0)                       // 2048*768 bf16
#define OFF_WBI  (OFF_UB  + 786432)                // 3200*768 bf16
#define OFF_WBO  (OFF_WBI + 1228800)               // 768*1536 bf16
#define OFF_ZX   (OFF_WBO + 589824)                // 2048*3200 f32
#define OFF_XBC  (OFF_ZX  + 6553600)               // 2048*1664 f32 (later aliased by y3)
#define OFF_DT   (OFF_XBC + 3407872)               // 2*192*1024 f32
#define OFF_ACS  (OFF_DT  + 393216)                // 2*192*8*128 f32
#define OFF_SC   (OFF_ACS + 393216)                // 16*128*128 f32
#define OFF_ST   (OFF_SC  + 262144)                // 16*64*1536 f32 [bc][n][hp]
#define OFF_PV   (OFF_ST  + 1572864)               // 16*64*1536 f32
#define OFF_Y    (OFF_PV  + 1572864)               // 2048*1536 f32
#define OFF_Y2B  (OFF_Y   + 3145728)               // 2048*1536 bf16

__device__ __forceinline__ float siluf(float x) { return x / (1.f + __expf(-x)); }

// ---------- transpose x (B,768,1024) -> ub bf16 (B*1024, 768) ----------
__global__ __launch_bounds__(256) void transpose_x_kernel(const float* __restrict__ x,
                                                          bf16_t* __restrict__ ub) {
  __shared__ float tile[32][33];
  int b = blockIdx.z;
  int d0 = blockIdx.x * 32, l0 = blockIdx.y * 32;
  int tx = threadIdx.x & 31, ty = threadIdx.x >> 5;
  for (int r = ty; r < 32; r += 8)
    tile[r][tx] = x[((size_t)(b * 768 + d0 + r)) * 1024 + l0 + tx];
  __syncthreads();
  for (int r = ty; r < 32; r += 8)
    ub[((size_t)(b * 1024 + l0 + r)) * 768 + d0 + tx] = (bf16_t)tile[tx][r];
}

// ---------- fp32 -> bf16 bulk convert ----------
__global__ __launch_bounds__(256) void cvt_bf16_kernel(const float* __restrict__ src,
                                                       bf16_t* __restrict__ dst, int n) {
  int i = (blockIdx.x * 256 + threadIdx.x) * 4;
  if (i < n) {
    float4 v = *(const float4*)(src + i);
    dst[i + 0] = (bf16_t)v.x; dst[i + 1] = (bf16_t)v.y;
    dst[i + 2] = (bf16_t)v.z; dst[i + 3] = (bf16_t)v.w;
  }
}

// ---------- bf16 MFMA GEMM: C[M][ldc @ n0..] = A[M][K] * B[N][K]^T ----------
template <int TMF>
__global__ __launch_bounds__(256) void gemm_mfma_bt(const bf16_t* __restrict__ A,
                                                    const bf16_t* __restrict__ B,
                                                    float* __restrict__ C,
                                                    int K, int ldc) {
  constexpr int RB = TMF * 32;
  constexpr int NA = RB / 32;
  __shared__ __align__(16) float smemf[8448];
  bf16_t* Asmem = (bf16_t*)smemf;
  bf16_t* Bsmem = Asmem + RB * 64;
  float* eps = smemf;

  int tid = threadIdx.x;
  int wave = tid >> 6, lane = tid & 63;
  int wr = wave >> 1, wc = wave & 1;

  int nwg = gridDim.x * gridDim.y;
  int flat = blockIdx.y * gridDim.x + blockIdx.x;
  int q = nwg >> 3;
  int swz = (flat & 7) * q + (flat >> 3);
  int bx = swz % gridDim.x, by = swz / gridDim.x;
  int m0 = by * RB, n0 = bx * 128;

  const bf16_t* Ag = A + (size_t)m0 * K;
  const bf16_t* Bg = B + (size_t)n0 * K;

  int aofs[NA]; const bf16_t* agp[NA];
#pragma unroll
  for (int i = 0; i < NA; ++i) {
    int id = i * 256 + tid;
    int r = id >> 3, c = id & 7;
    aofs[i] = r * 128 + ((c ^ (r & 7)) << 4);
    agp[i] = Ag + (size_t)r * K + c * 8;
  }
  int bofs[4]; const bf16_t* bgp[4];
#pragma unroll
  for (int i = 0; i < 4; ++i) {
    int id = i * 256 + tid;
    int r = id >> 3, c = id & 7;
    bofs[i] = r * 128 + ((c ^ (r & 7)) << 4);
    bgp[i] = Bg + (size_t)r * K + c * 8;
  }

  f32x4 acc[TMF][4] = {};
  uint4 areg[NA], breg[4];
#pragma unroll
  for (int i = 0; i < NA; ++i) areg[i] = *(const uint4*)(agp[i]);
#pragma unroll
  for (int i = 0; i < 4; ++i) breg[i] = *(const uint4*)(bgp[i]);

  for (int k0 = 0; k0 < K; k0 += 64) {
    __syncthreads();
#pragma unroll
    for (int i = 0; i < NA; ++i) *(uint4*)((char*)Asmem + aofs[i]) = areg[i];
#pragma unroll
    for (int i = 0; i < 4; ++i) *(uint4*)((char*)Bsmem + bofs[i]) = breg[i];
    __syncthreads();
    if (k0 + 64 < K) {
#pragma unroll
      for (int i = 0; i < NA; ++i) areg[i] = *(const uint4*)(agp[i] + k0 + 64);
#pragma unroll
      for (int i = 0; i < 4; ++i) breg[i] = *(const uint4*)(bgp[i] + k0 + 64);
    }
#pragma unroll
    for (int half = 0; half < 2; ++half) {
      int kk = half * 32;
      int ca = (kk >> 3) + (lane >> 4);
      bf16x8 af[TMF], bfr[4];
#pragma unroll
      for (int f = 0; f < TMF; ++f) {
        int Ra = wr * (TMF * 16) + f * 16 + (lane & 15);
        af[f] = *(const bf16x8*)((const char*)Asmem + Ra * 128 + ((ca ^ (Ra & 7)) << 4));
      }
#pragma unroll
      for (int f = 0; f < 4; ++f) {
        int Rb = wc * 64 + f * 16 + (lane & 15);
        bfr[f] = *(const bf16x8*)((const char*)Bsmem + Rb * 128 + ((ca ^ (Rb & 7)) << 4));
      }
#pragma unroll
      for (int i = 0; i < TMF; ++i)
#pragma unroll
        for (int j = 0; j < 4; ++j)
          acc[i][j] = __builtin_amdgcn_mfma_f32_16x16x32_bf16(af[i], bfr[j], acc[i][j], 0, 0, 0);
    }
  }

#pragma unroll
  for (int p = 0; p < RB / 64; ++p) {
    __syncthreads();
#pragma unroll
    for (int i = 0; i < TMF; ++i) {
      int rg = wr * (TMF * 16) + i * 16;
      if ((rg >> 6) == p) {
        int rl = (rg & 63) + ((lane >> 4) << 2);
#pragma unroll
        for (int j = 0; j < 4; ++j) {
          int col = wc * 64 + j * 16 + (lane & 15);
#pragma unroll
          for (int rr = 0; rr < 4; ++rr)
            eps[(rl + rr) * 132 + col] = acc[i][j][rr];
        }
      }
    }
    __syncthreads();
#pragma unroll
    for (int r = 0; r < 8; ++r) {
      int idx = tid + r * 256;
      int row = idx >> 5, c4 = (idx & 31) << 2;
      float4 v = *(const float4*)&eps[row * 132 + c4];
      *(float4*)&C[(size_t)(m0 + p * 64 + row) * ldc + n0 + c4] = v;
    }
  }
}

// ---------- fp32 dt projection + softplus -> dtb[(b*192+h)*1024+t] ----------
__global__ __launch_bounds__(256) void dtproj_kernel(const float* __restrict__ x,
                                                     const float* __restrict__ W_in,
                                                     const float* __restrict__ dt_bias,
                                                     float* __restrict__ dtb) {
  __shared__ float xs[32][128];
  __shared__ float wsm[8][32];
  int tid = threadIdx.x;
  int t0 = blockIdx.x * 128;
  int h0 = blockIdx.y * 8;
  int b = blockIdx.z;
  int t = tid & 127;
  int hh = tid >> 7;
  float acc[4] = {};
  const float* xb = x + (size_t)b * 768 * 1024 + t0;
  const float* wb = W_in + (size_t)(3200 + h0) * 768;
  for (int k0 = 0; k0 < 768; k0 += 32) {
#pragma unroll
    for (int r2 = 0; r2 < 4; ++r2) {
      int idx = tid + r2 * 256;
      int kk = idx >> 5, c4 = (idx & 31) << 2;
      *(float4*)&xs[kk][c4] = *(const float4*)&xb[(size_t)(k0 + kk) * 1024 + c4];
    }
    {
      int h = tid >> 5, kk = tid & 31;
      wsm[h][kk] = wb[(size_t)h * 768 + k0 + kk];
    }
    __syncthreads();
#pragma unroll
    for (int kk = 0; kk < 32; ++kk) {
      float xv = xs[kk][t];
#pragma unroll
      for (int j = 0; j < 4; ++j)
        acc[j] = fmaf(xv, wsm[hh * 4 + j][kk], acc[j]);
    }
    __syncthreads();
  }
#pragma unroll
  for (int j = 0; j < 4; ++j) {
    int h = h0 + hh * 4 + j;
    float v = acc[j] + dt_bias[h];
    dtb[((size_t)(b * 192 + h)) * 1024 + t0 + t] = (v > 20.f) ? v : log1pf(__expf(v));
  }
}

// ---------- depthwise causal conv + bias + silu ----------
__global__ __launch_bounds__(128) void conv_kernel(const float* __restrict__ zx,
                                                   const float* __restrict__ conv_w,
                                                   const float* __restrict__ conv_b,
                                                   float* __restrict__ xBC) {
  int ch = blockIdx.x * 128 + threadIdx.x;
  int m = blockIdx.y;
  int b = m >> 10, l = m & 1023;
  float acc = conv_b[ch];
#pragma unroll
  for (int j = 0; j < 4; ++j) {
    int tj = l - 3 + j;
    if (tj >= 0)
      acc = fmaf(conv_w[ch * 4 + j],
                 zx[((size_t)(b * 1024 + tj)) * 3200 + 1536 + ch], acc);
  }
  xBC[(size_t)m * 1664 + ch] = siluf(acc);
}

// ---------- per-chunk inclusive scan of dA ----------
__global__ __launch_bounds__(128) void scan_kernel(const float* __restrict__ dtb,
                                                   const float* __restrict__ A_log,
                                                   float* __restrict__ Acs) {
  __shared__ float s[128];
  int idx = blockIdx.x;
  int c = idx & 7;
  int bh = idx >> 3;
  int h = bh % 192;
  int l = threadIdx.x;
  float Ah = -__expf(A_log[h]);
  float v = dtb[(size_t)bh * 1024 + c * 128 + l] * Ah;
  s[l] = v;
  __syncthreads();
  for (int off = 1; off < 128; off <<= 1) {
    float add = (l >= off) ? s[l - off] : 0.f;
    __syncthreads();
    s[l] += add;
    __syncthreads();
  }
  Acs[(size_t)idx * 128 + l] = s[l];
}

// ---------- scores[l,s] = sum_n Cm[l,n]*Bm[s,n], per (b,c) ----------
__global__ __launch_bounds__(256) void scores_kernel(const float* __restrict__ xBC,
                                                     float* __restrict__ scores) {
  __shared__ float Cs[16][128];
  __shared__ float Bs[16][128];
  int bc = blockIdx.x;
  const float* base = xBC + (size_t)bc * 128 * 1664;
  int tx = threadIdx.x & 15, ty = threadIdx.x >> 4;
  float acc[8][8] = {};
  for (int n0 = 0; n0 < 64; n0 += 16) {
    for (int id = threadIdx.x; id < 2048; id += 256) {
      int lr = id >> 4, nn = id & 15;
      Cs[nn][lr] = base[(size_t)lr * 1664 + 1600 + n0 + nn];
      Bs[nn][lr] = base[(size_t)lr * 1664 + 1536 + n0 + nn];
    }
    __syncthreads();
#pragma unroll
    for (int nn = 0; nn < 16; ++nn) {
      float a[8], bb[8];
#pragma unroll
      for (int i = 0; i < 8; ++i) {
        a[i] = Cs[nn][ty * 8 + i];
        bb[i] = Bs[nn][tx * 8 + i];
      }
#pragma unroll
      for (int i = 0; i < 8; ++i)
#pragma unroll
        for (int j = 0; j < 8; ++j) acc[i][j] = fmaf(a[i], bb[j], acc[i][j]);
    }
    __syncthreads();
  }
  float* srow = scores + (size_t)bc * 16384;
#pragma unroll
  for (int i = 0; i < 8; ++i)
#pragma unroll
    for (int j = 0; j < 8; ++j)
      srow[(size_t)(ty * 8 + i) * 128 + tx * 8 + j] = acc[i][j];
}

// ---------- Y_diag via MFMA, per (b,c,h). 128 thr = 2 waves ----------
// Y[l][h*8+p] = sum_{s<=l} scores[l][s]*exp(acs[l]-acs[s]) * xdt[s][p]
__global__ __launch_bounds__(128) void diag_mfma_kernel(
    const float* __restrict__ xBC, const float* __restrict__ dtb,
    const float* __restrict__ Acs, const float* __restrict__ scores,
    float* __restrict__ Y) {
  __shared__ float sc_s[128][36];
  __shared__ float xdtT[8][132];
  __shared__ float acs_s[128];
  int idx = blockIdx.x;
  int h = idx % 192;
  int bc = idx / 192;
  int c = bc & 7, b = bc >> 3;
  int tid = threadIdx.x;
  int lane = tid & 63, wid = tid >> 6;

  acs_s[tid] = Acs[(((size_t)(b * 192 + h)) * 8 + c) * 128 + tid];
  {
    int p = tid & 7, s0 = (tid >> 3) * 8;
    const float* dtr = dtb + ((size_t)(b * 192 + h)) * 1024 + c * 128;
#pragma unroll
    for (int j = 0; j < 8; ++j) {
      int s = s0 + j;
      xdtT[p][s] = xBC[((size_t)(bc * 128 + s)) * 1664 + h * 8 + p] * dtr[s];
    }
  }

  f32x4 acc[4] = {};
  const float* sall = scores + (size_t)bc * 16384;
  for (int ks = 0; ks < 4; ++ks) {
    __syncthreads();
#pragma unroll
    for (int i = 0; i < 8; ++i) {
      int id = tid + i * 128;
      int l = id >> 3, c4 = (id & 7) * 4;
      *(float4*)&sc_s[l][c4] = *(const float4*)&sall[(size_t)l * 128 + ks * 32 + c4];
    }
    __syncthreads();

    bf16x8 bfv;
    {
      int p = lane & 7;
      int sb = (lane >> 4) * 8;
      float4 v0 = *(const float4*)&xdtT[p][ks * 32 + sb];
      float4 v1 = *(const float4*)&xdtT[p][ks * 32 + sb + 4];
      bfv[0] = (bf16_t)v0.x; bfv[1] = (bf16_t)v0.y; bfv[2] = (bf16_t)v0.z; bfv[3] = (bf16_t)v0.w;
      bfv[4] = (bf16_t)v1.x; bfv[5] = (bf16_t)v1.y; bfv[6] = (bf16_t)v1.z; bfv[7] = (bf16_t)v1.w;
    }
#pragma unroll
    for (int mf = 0; mf < 4; ++mf) {
      int lbase = (mf * 2 + wid) * 16;
      if (ks * 32 > lbase + 15) continue;
      int l = lbase + (lane & 15);
      float al = acs_s[l];
      int sb = (lane >> 4) * 8;
      int sg = ks * 32 + sb;
      float4 s0 = *(const float4*)&sc_s[l][sb];
      float4 s1 = *(const float4*)&sc_s[l][sb + 4];
      float4 e0 = *(const float4*)&acs_s[sg];
      float4 e1 = *(const float4*)&acs_s[sg + 4];
      float sv[8] = {s0.x, s0.y, s0.z, s0.w, s1.x, s1.y, s1.z, s1.w};
      float ev[8] = {e0.x, e0.y, e0.z, e0.w, e1.x, e1.y, e1.z, e1.w};
      bf16x8 af;
#pragma unroll
      for (int j = 0; j < 8; ++j) {
        float v = sv[j] * __expf(al - ev[j]);
        af[j] = (bf16_t)((sg + j <= l) ? v : 0.f);
      }
      acc[mf] = __builtin_amdgcn_mfma_f32_16x16x32_bf16(af, bfv, acc[mf], 0, 0, 0);
    }
  }

  int p = lane & 15;
  if (p < 8) {
    int rg = (lane >> 4) * 4;
#pragma unroll
    for (int mf = 0; mf < 4; ++mf) {
      int lbase = (mf * 2 + wid) * 16;
      float* yp = Y + ((size_t)(bc * 128 + lbase + rg)) * 1536 + h * 8 + p;
#pragma unroll
      for (int rr = 0; rr < 4; ++rr)
        yp[(size_t)rr * 1536] = acc[mf][rr];
    }
  }
}

// ---------- chunk states via MFMA, per (bc, 16-head tile) ----------
// st2[bc][n][hp] = sum_s B[s][n] * x[s][hp]*dt*decay  (M=64,N=128,K=128)
__global__ __launch_bounds__(256) void states_mfma_kernel(
    const float* __restrict__ xBC, const float* __restrict__ dtb,
    const float* __restrict__ Acs, float* __restrict__ st2) {
  __shared__ bf16_t Asm[64 * 128];
  __shared__ bf16_t Wsm[128 * 128];
  __shared__ float dcoef[16][128];
  int tile = blockIdx.x;
  int bc = blockIdx.y;
  int c = bc & 7, b = bc >> 3;
  int hg0 = tile * 16;
  int tid = threadIdx.x;
  int wave = tid >> 6, lane = tid & 63;

#pragma unroll
  for (int i = 0; i < 8; ++i) {
    int id = tid + i * 256;
    int hh = id >> 7, s = id & 127;
    int h = hg0 + hh;
    const float* ar = Acs + (((size_t)(b * 192 + h)) * 8 + c) * 128;
    float dv = dtb[((size_t)(b * 192 + h)) * 1024 + c * 128 + s];
    dcoef[hh][s] = dv * __expf(ar[127] - ar[s]);
  }
#pragma unroll
  for (int i = 0; i < 32; ++i) {
    int id = tid + i * 256;
    int s = id >> 6, n = id & 63;
    float v = xBC[((size_t)(bc * 128 + s)) * 1664 + 1536 + n];
    int byte = n * 256 + (((s >> 3) ^ (n & 7)) << 4) + (s & 7) * 2;
    *(bf16_t*)((char*)Asm + byte) = (bf16_t)v;
  }
  __syncthreads();
#pragma unroll
  for (int i = 0; i < 64; ++i) {
    int id = tid + i * 256;
    int s = id >> 7, hp = id & 127;
    float v = xBC[((size_t)(bc * 128 + s)) * 1664 + hg0 * 8 + hp] * dcoef[hp >> 3][s];
    int byte = hp * 256 + (((s >> 3) ^ (hp & 7)) << 4) + (s & 7) * 2;
    *(bf16_t*)((char*)Wsm + byte) = (bf16_t)v;
  }
  __syncthreads();

  f32x4 acc[4][2] = {};
#pragma unroll
  for (int ks = 0; ks < 4; ++ks) {
    int cc = ks * 4 + (lane >> 4);
    bf16x8 af[4], bfr[2];
#pragma unroll
    for (int i = 0; i < 4; ++i) {
      int Ra = i * 16 + (lane & 15);
      af[i] = *(const bf16x8*)((const char*)Asm + Ra * 256 + ((cc ^ (Ra & 7)) << 4));
    }
#pragma unroll
    for (int j = 0; j < 2; ++j) {
      int Rb = wave * 32 + j * 16 + (lane & 15);
      bfr[j] = *(const bf16x8*)((const char*)Wsm + Rb * 256 + ((cc ^ (Rb & 7)) << 4));
    }
#pragma unroll
    for (int i = 0; i < 4; ++i)
#pragma unroll
      for (int j = 0; j < 2; ++j)
        acc[i][j] = __builtin_amdgcn_mfma_f32_16x16x32_bf16(af[i], bfr[j], acc[i][j], 0, 0, 0);
  }
#pragma unroll
  for (int i = 0; i < 4; ++i)
#pragma unroll
    for (int j = 0; j < 2; ++j) {
      int n = i * 16 + ((lane >> 4) << 2);
      int col = tile * 128 + wave * 32 + j * 16 + (lane & 15);
      float* sp = st2 + (size_t)bc * 98304 + (size_t)n * 1536 + col;
#pragma unroll
      for (int rr = 0; rr < 4; ++rr) sp[(size_t)rr * 1536] = acc[i][j][rr];
    }
}

// ---------- inter-chunk recurrence, per (b,h); layout [bc][n][hp] ----------
__global__ __launch_bounds__(512) void recur_kernel(const float* __restrict__ Acs,
                                                    const float* __restrict__ states,
                                                    float* __restrict__ prev) {
  int bh = blockIdx.x;
  int b = bh / 192, h = bh % 192;
  int tid = threadIdx.x;
  int n = tid >> 3, p = tid & 7;
  float s_run = 0.f;
  for (int c = 0; c < 8; ++c) {
    size_t o = (size_t)(b * 8 + c) * 98304 + (size_t)n * 1536 + h * 8 + p;
    prev[o] = s_run;
    float dAs = Acs[(((size_t)(b * 192 + h)) * 8 + c) * 128 + 127];
    s_run = s_run * __expf(dAs) + states[o];
  }
}

// ---------- Y_off + D*xh, per (b,c,h) ----------
__global__ __launch_bounds__(128) void yoff_kernel(const float* __restrict__ xBC,
                                                   const float* __restrict__ Acs,
                                                   const float* __restrict__ prev,
                                                   const float* __restrict__ Dvec,
                                                   float* __restrict__ Y) {
  __shared__ float pv_s[512];
  int idx = blockIdx.x;
  int h = idx % 192;
  int bc = idx / 192;
  int c = bc & 7, b = bc >> 3;
  int l = threadIdx.x;
  const float* pb = prev + (size_t)bc * 98304 + h * 8;
  for (int id = l; id < 512; id += 128)
    pv_s[(id & 7) * 64 + (id >> 3)] = pb[(size_t)(id >> 3) * 1536 + (id & 7)];
  __syncthreads();
  size_t rowt = (size_t)b * 1024 + c * 128 + l;
  float eacs = __expf(Acs[(((size_t)(b * 192 + h)) * 8 + c) * 128 + l]);
  const float* crow = xBC + rowt * 1664 + 1600;
  float acc[8] = {0, 0, 0, 0, 0, 0, 0, 0};
  for (int n = 0; n < 64; n += 4) {
    float4 cv = *(const float4*)&crow[n];
#pragma unroll
    for (int p = 0; p < 8; ++p) {
      acc[p] = fmaf(cv.x, pv_s[p * 64 + n + 0], acc[p]);
      acc[p] = fmaf(cv.y, pv_s[p * 64 + n + 1], acc[p]);
      acc[p] = fmaf(cv.z, pv_s[p * 64 + n + 2], acc[p]);
      acc[p] = fmaf(cv.w, pv_s[p * 64 + n + 3], acc[p]);
    }
  }
  float Dh = Dvec[h];
  const float* xrow = xBC + rowt * 1664 + h * 8;
  float* yrow = Y + rowt * 1536 + h * 8;
#pragma unroll
  for (int p = 0; p < 8; ++p) yrow[p] += acc[p] * eacs + Dh * xrow[p];
}

// ---------- gate with silu(z) + RMSNorm -> y2 bf16 ----------
__global__ __launch_bounds__(256) void gatenorm_kernel(const float* __restrict__ Y,
                                                       const float* __restrict__ zx,
                                                       const float* __restrict__ norm_w,
                                                       bf16_t* __restrict__ y2b) {
  int m = blockIdx.x;
  int tid = threadIdx.x;
  const float* yrow = Y + (size_t)m * 1536;
  const float* zrow = zx + (size_t)m * 3200;
  float vals[6];
  float ss = 0.f;
#pragma unroll
  for (int r = 0; r < 6; ++r) {
    int i = tid + r * 256;
    float v = yrow[i] * siluf(zrow[i]);
    vals[r] = v;
    ss = fmaf(v, v, ss);
  }
#pragma unroll
  for (int off = 32; off > 0; off >>= 1) ss += __shfl_down(ss, off);
  __shared__ float red[4];
  int lane = tid & 63, wid = tid >> 6;
  if (lane == 0) red[wid] = ss;
  __syncthreads();
  float tot = red[0] + red[1] + red[2] + red[3];
  float scale = rsqrtf(tot * (1.f / 1536.f) + 1e-5f);
#pragma unroll
  for (int r = 0; r < 6; ++r) {
    int i = tid + r * 256;
    y2b[(size_t)m * 1536 + i] = (bf16_t)(vals[r] * scale * norm_w[i]);
  }
}

// ---------- transpose y3 (B*1024,768) -> out (B,768,1024) ----------
__global__ __launch_bounds__(256) void transpose_out_kernel(const float* __restrict__ y3,
                                                            float* __restrict__ out) {
  __shared__ float tile[32][33];
  int b = blockIdx.z;
  int d0 = blockIdx.x * 32, l0 = blockIdx.y * 32;
  int tx = threadIdx.x & 31, ty = threadIdx.x >> 5;
  for (int r = ty; r < 32; r += 8)
    tile[r][tx] = y3[((size_t)(b * 1024 + l0 + r)) * 768 + d0 + tx];
  __syncthreads();
  for (int r = ty; r < 32; r += 8)
    out[((size_t)(b * 768 + d0 + r)) * 1024 + l0 + tx] = tile[tx][r];
}

extern "C" void kernel_launch(void* const* d_in, const int* in_sizes, int n_in,
                              void* d_out, int out_size, void* d_ws, size_t ws_size,
                              hipStream_t stream) {
  const float* x = (const float*)d_in[0];
  const float* W_in = (const float*)d_in[1];
  const float* conv_w = (const float*)d_in[2];
  const float* conv_b = (const float*)d_in[3];
  const float* dt_bias = (const float*)d_in[4];
  const float* A_log = (const float*)d_in[5];
  const float* Dvec = (const float*)d_in[6];
  const float* norm_w = (const float*)d_in[7];
  const float* W_out = (const float*)d_in[8];
  float* out = (float*)d_out;
  float* ws = (float*)d_ws;

  bf16_t* ub = (bf16_t*)(ws + OFF_UB);
  bf16_t* Wbi = (bf16_t*)(ws + OFF_WBI);
  bf16_t* Wbo = (bf16_t*)(ws + OFF_WBO);
  float* zx = ws + OFF_ZX;
  float* xBC = ws + OFF_XBC;
  float* y3 = ws + OFF_XBC;
  float* dtb = ws + OFF_DT;
  float* Acs = ws + OFF_ACS;
  float* sc = ws + OFF_SC;
  float* st = ws + OFF_ST;
  float* pv = ws + OFF_PV;
  float* Yb = ws + OFF_Y;
  bf16_t* y2b = (bf16_t*)(ws + OFF_Y2B);

  transpose_x_kernel<<<dim3(24, 32, 2), 256, 0, stream>>>(x, ub);
  cvt_bf16_kernel<<<2400, 256, 0, stream>>>(W_in, Wbi, 3200 * 768);
  cvt_bf16_kernel<<<1152, 256, 0, stream>>>(W_out, Wbo, 768 * 1536);
  gemm_mfma_bt<4><<<dim3(25, 16), 256, 0, stream>>>(ub, Wbi, zx, 768, 3200);
  dtproj_kernel<<<dim3(8, 24, 2), 256, 0, stream>>>(x, W_in, dt_bias, dtb);
  conv_kernel<<<dim3(13, 2048), 128, 0, stream>>>(zx, conv_w, conv_b, xBC);
  scan_kernel<<<3072, 128, 0, stream>>>(dtb, A_log, Acs);
  scores_kernel<<<16, 256, 0, stream>>>(xBC, sc);
  diag_mfma_kernel<<<3072, 128, 0, stream>>>(xBC, dtb, Acs, sc, Yb);
  states_mfma_kernel<<<dim3(12, 16), 256, 0, stream>>>(xBC, dtb, Acs, st);
  recur_kernel<<<384, 512, 0, stream>>>(Acs, st, pv);
  yoff_kernel<<<3072, 128, 0, stream>>>(xBC, Acs, pv, Dvec, Yb);
  gatenorm_kernel<<<2048, 256, 0, stream>>>(Yb, zx, norm_w, y2b);
  gemm_mfma_bt<2><<<dim3(6, 32), 256, 0, stream>>>(y2b, Wbo, y3, 1536, 768);
  transpose_out_kernel<<<dim3(24, 32, 2), 256, 0, stream>>>(y3, out);
}

// Round 5
// 257.741 us; speedup vs baseline: 1.7926x; 1.0917x over previous
//
#include <hip/hip_runtime.h>
#include <cstddef>
#include <cstdint>

// Mamba2 forward. bf16 MFMA GEMMs + bf16 intermediates to cut HBM writes.
// B=2 L=1024 DMODEL=768 DINNER=1536 NHEADS=192 P=8 N=64 CONVDIM=1664

typedef __bf16 bf16_t;
typedef bf16_t bf16x2 __attribute__((ext_vector_type(2)));
typedef bf16_t bf16x4 __attribute__((ext_vector_type(4)));
typedef bf16_t bf16x8 __attribute__((ext_vector_type(8)));
typedef float f32x4 __attribute__((ext_vector_type(4)));

// ---------------- ws layout (float units) ----------------
#define OFF_UB   ((size_t)0)                 // 2048*768 bf16
#define OFF_WBI  (OFF_UB  + 786432)          // 3200*768 bf16
#define OFF_WBO  (OFF_WBI + 1228800)         // 768*1536 bf16
#define OFF_ZX   (OFF_WBO + 589824)          // 2048*3200 bf16
#define OFF_XBC  (OFF_ZX  + 3276800)         // 2048*1664 bf16
#define OFF_DT   (OFF_XBC + 1703936)         // 2*192*1024 f32
#define OFF_ACS  (OFF_DT  + 393216)          // 2*192*8*128 f32
#define OFF_SC   (OFF_ACS + 393216)          // 16*128*128 f32
#define OFF_ST   (OFF_SC  + 262144)          // 16*64*1536 f32 [bc][n][hp]
#define OFF_PV   (OFF_ST  + 1572864)         // 16*1536*64 f32 [bc][hp][n]
#define OFF_Y    (OFF_PV  + 1572864)         // 2048*1536 f32
#define OFF_Y2B  (OFF_Y   + 3145728)         // 2048*1536 bf16

__device__ __forceinline__ float siluf(float x) { return x / (1.f + __expf(-x)); }

// ---------- transpose x (B,768,1024) -> ub bf16 (B*1024, 768) ----------
__global__ __launch_bounds__(256) void transpose_x_kernel(const float* __restrict__ x,
                                                          bf16_t* __restrict__ ub) {
  __shared__ float tile[32][33];
  int b = blockIdx.z;
  int d0 = blockIdx.x * 32, l0 = blockIdx.y * 32;
  int tx = threadIdx.x & 31, ty = threadIdx.x >> 5;
  for (int r = ty; r < 32; r += 8)
    tile[r][tx] = x[((size_t)(b * 768 + d0 + r)) * 1024 + l0 + tx];
  __syncthreads();
  for (int r = ty; r < 32; r += 8)
    ub[((size_t)(b * 1024 + l0 + r)) * 768 + d0 + tx] = (bf16_t)tile[tx][r];
}

// ---------- fp32 -> bf16 bulk convert ----------
__global__ __launch_bounds__(256) void cvt_bf16_kernel(const float* __restrict__ src,
                                                       bf16_t* __restrict__ dst, int n) {
  int i = (blockIdx.x * 256 + threadIdx.x) * 4;
  if (i < n) {
    float4 v = *(const float4*)(src + i);
    bf16x4 o = {(bf16_t)v.x, (bf16_t)v.y, (bf16_t)v.z, (bf16_t)v.w};
    *(bf16x4*)(dst + i) = o;
  }
}

// ---------- bf16 MFMA GEMM: tile (TMF*32) x 128, BK=64 ----------
// OM=0: store bf16 row-major with ldc. OM=1: store f32 transposed to
// out(B,768,1024): row m -> (b= m>>10, l= m&1023), col -> channel n0+col.
template <int TMF, int OM>
__global__ __launch_bounds__(256) void gemm_mfma_bt(const bf16_t* __restrict__ A,
                                                    const bf16_t* __restrict__ B,
                                                    void* __restrict__ Cv,
                                                    int K, int ldc) {
  constexpr int RB = TMF * 32;
  constexpr int NA = RB / 32;
  __shared__ __align__(16) float smemf[8448];
  bf16_t* Asmem = (bf16_t*)smemf;
  bf16_t* Bsmem = Asmem + RB * 64;
  float* eps = smemf;

  int tid = threadIdx.x;
  int wave = tid >> 6, lane = tid & 63;
  int wr = wave >> 1, wc = wave & 1;

  int nwg = gridDim.x * gridDim.y;
  int flat = blockIdx.y * gridDim.x + blockIdx.x;
  int q = nwg >> 3;
  int swz = (flat & 7) * q + (flat >> 3);
  int bx = swz % gridDim.x, by = swz / gridDim.x;
  int m0 = by * RB, n0 = bx * 128;

  const bf16_t* Ag = A + (size_t)m0 * K;
  const bf16_t* Bg = B + (size_t)n0 * K;

  int aofs[NA]; const bf16_t* agp[NA];
#pragma unroll
  for (int i = 0; i < NA; ++i) {
    int id = i * 256 + tid;
    int r = id >> 3, c = id & 7;
    aofs[i] = r * 128 + ((c ^ (r & 7)) << 4);
    agp[i] = Ag + (size_t)r * K + c * 8;
  }
  int bofs[4]; const bf16_t* bgp[4];
#pragma unroll
  for (int i = 0; i < 4; ++i) {
    int id = i * 256 + tid;
    int r = id >> 3, c = id & 7;
    bofs[i] = r * 128 + ((c ^ (r & 7)) << 4);
    bgp[i] = Bg + (size_t)r * K + c * 8;
  }

  f32x4 acc[TMF][4] = {};
  uint4 areg[NA], breg[4];
#pragma unroll
  for (int i = 0; i < NA; ++i) areg[i] = *(const uint4*)(agp[i]);
#pragma unroll
  for (int i = 0; i < 4; ++i) breg[i] = *(const uint4*)(bgp[i]);

  for (int k0 = 0; k0 < K; k0 += 64) {
    __syncthreads();
#pragma unroll
    for (int i = 0; i < NA; ++i) *(uint4*)((char*)Asmem + aofs[i]) = areg[i];
#pragma unroll
    for (int i = 0; i < 4; ++i) *(uint4*)((char*)Bsmem + bofs[i]) = breg[i];
    __syncthreads();
    if (k0 + 64 < K) {
#pragma unroll
      for (int i = 0; i < NA; ++i) areg[i] = *(const uint4*)(agp[i] + k0 + 64);
#pragma unroll
      for (int i = 0; i < 4; ++i) breg[i] = *(const uint4*)(bgp[i] + k0 + 64);
    }
#pragma unroll
    for (int half = 0; half < 2; ++half) {
      int kk = half * 32;
      int ca = (kk >> 3) + (lane >> 4);
      bf16x8 af[TMF], bfr[4];
#pragma unroll
      for (int f = 0; f < TMF; ++f) {
        int Ra = wr * (TMF * 16) + f * 16 + (lane & 15);
        af[f] = *(const bf16x8*)((const char*)Asmem + Ra * 128 + ((ca ^ (Ra & 7)) << 4));
      }
#pragma unroll
      for (int f = 0; f < 4; ++f) {
        int Rb = wc * 64 + f * 16 + (lane & 15);
        bfr[f] = *(const bf16x8*)((const char*)Bsmem + Rb * 128 + ((ca ^ (Rb & 7)) << 4));
      }
#pragma unroll
      for (int i = 0; i < TMF; ++i)
#pragma unroll
        for (int j = 0; j < 4; ++j)
          acc[i][j] = __builtin_amdgcn_mfma_f32_16x16x32_bf16(af[i], bfr[j], acc[i][j], 0, 0, 0);
    }
  }

#pragma unroll
  for (int p = 0; p < RB / 64; ++p) {
    __syncthreads();
#pragma unroll
    for (int i = 0; i < TMF; ++i) {
      int rg = wr * (TMF * 16) + i * 16;
      if ((rg >> 6) == p) {
        int rl = (rg & 63) + ((lane >> 4) << 2);
#pragma unroll
        for (int j = 0; j < 4; ++j) {
          int col = wc * 64 + j * 16 + (lane & 15);
#pragma unroll
          for (int rr = 0; rr < 4; ++rr)
            eps[(rl + rr) * 132 + col] = acc[i][j][rr];
        }
      }
    }
    __syncthreads();
    if (OM == 0) {
      bf16_t* Cb = (bf16_t*)Cv;
#pragma unroll
      for (int r = 0; r < 8; ++r) {
        int idx = tid + r * 256;
        int row = idx >> 5, c4 = (idx & 31) << 2;
        float4 v = *(const float4*)&eps[row * 132 + c4];
        bf16x4 o = {(bf16_t)v.x, (bf16_t)v.y, (bf16_t)v.z, (bf16_t)v.w};
        *(bf16x4*)&Cb[(size_t)(m0 + p * 64 + row) * ldc + n0 + c4] = o;
      }
    } else {
      float* Cf = (float*)Cv;
      int b = m0 >> 10, l0 = m0 & 1023;
#pragma unroll
      for (int cg = 0; cg < 8; ++cg) {
        int col = cg * 16 + (tid >> 4);
        int rr = (tid & 15) * 4;
        float4 v = make_float4(eps[(rr + 0) * 132 + col], eps[(rr + 1) * 132 + col],
                               eps[(rr + 2) * 132 + col], eps[(rr + 3) * 132 + col]);
        *(float4*)&Cf[((size_t)(b * 768 + n0 + col)) * 1024 + l0 + rr] = v;
      }
    }
  }
}

// ---------- fp32 dt projection + softplus -> dtb[(b*192+h)*1024+t] ----------
__global__ __launch_bounds__(256) void dtproj_kernel(const float* __restrict__ x,
                                                     const float* __restrict__ W_in,
                                                     const float* __restrict__ dt_bias,
                                                     float* __restrict__ dtb) {
  __shared__ float xs[32][128];
  __shared__ float wsm[8][32];
  int tid = threadIdx.x;
  int t0 = blockIdx.x * 128;
  int h0 = blockIdx.y * 8;
  int b = blockIdx.z;
  int t = tid & 127;
  int hh = tid >> 7;
  float acc[4] = {};
  const float* xb = x + (size_t)b * 768 * 1024 + t0;
  const float* wb = W_in + (size_t)(3200 + h0) * 768;
  for (int k0 = 0; k0 < 768; k0 += 32) {
#pragma unroll
    for (int r2 = 0; r2 < 4; ++r2) {
      int idx = tid + r2 * 256;
      int kk = idx >> 5, c4 = (idx & 31) << 2;
      *(float4*)&xs[kk][c4] = *(const float4*)&xb[(size_t)(k0 + kk) * 1024 + c4];
    }
    {
      int h = tid >> 5, kk = tid & 31;
      wsm[h][kk] = wb[(size_t)h * 768 + k0 + kk];
    }
    __syncthreads();
#pragma unroll
    for (int kk = 0; kk < 32; ++kk) {
      float xv = xs[kk][t];
#pragma unroll
      for (int j = 0; j < 4; ++j)
        acc[j] = fmaf(xv, wsm[hh * 4 + j][kk], acc[j]);
    }
    __syncthreads();
  }
#pragma unroll
  for (int j = 0; j < 4; ++j) {
    int h = h0 + hh * 4 + j;
    float v = acc[j] + dt_bias[h];
    dtb[((size_t)(b * 192 + h)) * 1024 + t0 + t] = (v > 20.f) ? v : log1pf(__expf(v));
  }
}

// ---------- depthwise causal conv + bias + silu (bf16 in/out, 2ch/thr) ----------
__global__ __launch_bounds__(128) void conv_kernel(const bf16_t* __restrict__ zxb,
                                                   const float* __restrict__ conv_w,
                                                   const float* __restrict__ conv_b,
                                                   bf16_t* __restrict__ xBC) {
  int ch2 = blockIdx.x * 128 + threadIdx.x;
  if (ch2 >= 832) return;
  int ch = ch2 * 2;
  int m = blockIdx.y;
  int b = m >> 10, l = m & 1023;
  float a0 = conv_b[ch], a1 = conv_b[ch + 1];
  const bf16_t* base = zxb + (size_t)b * 1024 * 3200 + 1536 + ch;
#pragma unroll
  for (int j = 0; j < 4; ++j) {
    int tj = l - 3 + j;
    if (tj >= 0) {
      bf16x2 v = *(const bf16x2*)&base[(size_t)tj * 3200];
      a0 = fmaf(conv_w[ch * 4 + j], (float)v[0], a0);
      a1 = fmaf(conv_w[(ch + 1) * 4 + j], (float)v[1], a1);
    }
  }
  bf16x2 o = {(bf16_t)siluf(a0), (bf16_t)siluf(a1)};
  *(bf16x2*)&xBC[(size_t)m * 1664 + ch] = o;
}

// ---------- per-chunk inclusive scan of dA ----------
__global__ __launch_bounds__(128) void scan_kernel(const float* __restrict__ dtb,
                                                   const float* __restrict__ A_log,
                                                   float* __restrict__ Acs) {
  __shared__ float s[128];
  int idx = blockIdx.x;
  int c = idx & 7;
  int bh = idx >> 3;
  int h = bh % 192;
  int l = threadIdx.x;
  float Ah = -__expf(A_log[h]);
  float v = dtb[(size_t)bh * 1024 + c * 128 + l] * Ah;
  s[l] = v;
  __syncthreads();
  for (int off = 1; off < 128; off <<= 1) {
    float add = (l >= off) ? s[l - off] : 0.f;
    __syncthreads();
    s[l] += add;
    __syncthreads();
  }
  Acs[(size_t)idx * 128 + l] = s[l];
}

// ---------- scores[l,s] = sum_n Cm[l,n]*Bm[s,n], per (b,c) ----------
__global__ __launch_bounds__(256) void scores_kernel(const bf16_t* __restrict__ xBC,
                                                     float* __restrict__ scores) {
  __shared__ float Cs[16][128];
  __shared__ float Bs[16][128];
  int bc = blockIdx.x;
  const bf16_t* base = xBC + (size_t)bc * 128 * 1664;
  int tx = threadIdx.x & 15, ty = threadIdx.x >> 4;
  float acc[8][8] = {};
  for (int n0 = 0; n0 < 64; n0 += 16) {
    for (int id = threadIdx.x; id < 2048; id += 256) {
      int lr = id >> 4, nn = id & 15;
      Cs[nn][lr] = (float)base[(size_t)lr * 1664 + 1600 + n0 + nn];
      Bs[nn][lr] = (float)base[(size_t)lr * 1664 + 1536 + n0 + nn];
    }
    __syncthreads();
#pragma unroll
    for (int nn = 0; nn < 16; ++nn) {
      float a[8], bb[8];
#pragma unroll
      for (int i = 0; i < 8; ++i) {
        a[i] = Cs[nn][ty * 8 + i];
        bb[i] = Bs[nn][tx * 8 + i];
      }
#pragma unroll
      for (int i = 0; i < 8; ++i)
#pragma unroll
        for (int j = 0; j < 8; ++j) acc[i][j] = fmaf(a[i], bb[j], acc[i][j]);
    }
    __syncthreads();
  }
  float* srow = scores + (size_t)bc * 16384;
#pragma unroll
  for (int i = 0; i < 8; ++i)
#pragma unroll
    for (int j = 0; j < 8; ++j)
      srow[(size_t)(ty * 8 + i) * 128 + tx * 8 + j] = acc[i][j];
}

// ---------- chunk states via MFMA, per (bc, 16-head tile) ----------
__global__ __launch_bounds__(256) void states_mfma_kernel(
    const bf16_t* __restrict__ xBC, const float* __restrict__ dtb,
    const float* __restrict__ Acs, float* __restrict__ st2) {
  __shared__ bf16_t Asm[64 * 128];
  __shared__ bf16_t Wsm[128 * 128];
  __shared__ float dcoef[16][128];
  int tile = blockIdx.x;
  int bc = blockIdx.y;
  int c = bc & 7, b = bc >> 3;
  int hg0 = tile * 16;
  int tid = threadIdx.x;
  int wave = tid >> 6, lane = tid & 63;

#pragma unroll
  for (int i = 0; i < 8; ++i) {
    int id = tid + i * 256;
    int hh = id >> 7, s = id & 127;
    int h = hg0 + hh;
    const float* ar = Acs + (((size_t)(b * 192 + h)) * 8 + c) * 128;
    float dv = dtb[((size_t)(b * 192 + h)) * 1024 + c * 128 + s];
    dcoef[hh][s] = dv * __expf(ar[127] - ar[s]);
  }
#pragma unroll
  for (int i = 0; i < 32; ++i) {
    int id = tid + i * 256;
    int s = id >> 6, n = id & 63;
    float v = (float)xBC[((size_t)(bc * 128 + s)) * 1664 + 1536 + n];
    int byte = n * 256 + (((s >> 3) ^ (n & 7)) << 4) + (s & 7) * 2;
    *(bf16_t*)((char*)Asm + byte) = (bf16_t)v;
  }
  __syncthreads();
#pragma unroll
  for (int i = 0; i < 64; ++i) {
    int id = tid + i * 256;
    int s = id >> 7, hp = id & 127;
    float v = (float)xBC[((size_t)(bc * 128 + s)) * 1664 + hg0 * 8 + hp] * dcoef[hp >> 3][s];
    int byte = hp * 256 + (((s >> 3) ^ (hp & 7)) << 4) + (s & 7) * 2;
    *(bf16_t*)((char*)Wsm + byte) = (bf16_t)v;
  }
  __syncthreads();

  f32x4 acc[4][2] = {};
#pragma unroll
  for (int ks = 0; ks < 4; ++ks) {
    int cc = ks * 4 + (lane >> 4);
    bf16x8 af[4], bfr[2];
#pragma unroll
    for (int i = 0; i < 4; ++i) {
      int Ra = i * 16 + (lane & 15);
      af[i] = *(const bf16x8*)((const char*)Asm + Ra * 256 + ((cc ^ (Ra & 7)) << 4));
    }
#pragma unroll
    for (int j = 0; j < 2; ++j) {
      int Rb = wave * 32 + j * 16 + (lane & 15);
      bfr[j] = *(const bf16x8*)((const char*)Wsm + Rb * 256 + ((cc ^ (Rb & 7)) << 4));
    }
#pragma unroll
    for (int i = 0; i < 4; ++i)
#pragma unroll
      for (int j = 0; j < 2; ++j)
        acc[i][j] = __builtin_amdgcn_mfma_f32_16x16x32_bf16(af[i], bfr[j], acc[i][j], 0, 0, 0);
  }
#pragma unroll
  for (int i = 0; i < 4; ++i)
#pragma unroll
    for (int j = 0; j < 2; ++j) {
      int n = i * 16 + ((lane >> 4) << 2);
      int col = tile * 128 + wave * 32 + j * 16 + (lane & 15);
      float* sp = st2 + (size_t)bc * 98304 + (size_t)n * 1536 + col;
#pragma unroll
      for (int rr = 0; rr < 4; ++rr) sp[(size_t)rr * 1536] = acc[i][j][rr];
    }
}

// ---------- inter-chunk recurrence; st [bc][n][hp] -> pv [bc][hp][n] ----------
__global__ __launch_bounds__(512) void recur_kernel(const float* __restrict__ Acs,
                                                    const float* __restrict__ states,
                                                    float* __restrict__ prev) {
  int bh = blockIdx.x;
  int b = bh / 192, h = bh % 192;
  int tid = threadIdx.x;
  int p = tid >> 6, n = tid & 63;
  float s_run = 0.f;
  for (int c = 0; c < 8; ++c) {
    size_t base = (size_t)(b * 8 + c) * 98304;
    prev[base + (size_t)(h * 8 + p) * 64 + n] = s_run;
    float dAs = Acs[(((size_t)(b * 192 + h)) * 8 + c) * 128 + 127];
    s_run = s_run * __expf(dAs) + states[base + (size_t)n * 1536 + h * 8 + p];
  }
}

// ---------- Y = Y_diag + Y_off + D*x via MFMA, per (b,c,h), 128 thr ----------
__global__ __launch_bounds__(128) void ydiag_off_kernel(
    const bf16_t* __restrict__ xBC, const float* __restrict__ dtb,
    const float* __restrict__ Acs, const float* __restrict__ scores,
    const float* __restrict__ pv, const float* __restrict__ Dvec,
    float* __restrict__ Y) {
  __shared__ float sc_s[128][36];
  __shared__ float xdtT[8][132];
  __shared__ float acs_s[128];
  __shared__ float pv_s[512];
  int idx = blockIdx.x;
  int h = idx % 192;
  int bc = idx / 192;
  int c = bc & 7, b = bc >> 3;
  int tid = threadIdx.x;
  int lane = tid & 63, wid = tid >> 6;

  acs_s[tid] = Acs[(((size_t)(b * 192 + h)) * 8 + c) * 128 + tid];
  {
    int p = tid & 7, s0 = (tid >> 3) * 8;
    const float* dtr = dtb + ((size_t)(b * 192 + h)) * 1024 + c * 128;
#pragma unroll
    for (int j = 0; j < 8; ++j) {
      int s = s0 + j;
      xdtT[p][s] = (float)xBC[((size_t)(bc * 128 + s)) * 1664 + h * 8 + p] * dtr[s];
    }
  }
  {
    const float* pb = pv + (size_t)bc * 98304 + (size_t)h * 512;
    *(float4*)&pv_s[tid * 4] = *(const float4*)&pb[tid * 4];
  }

  f32x4 acc[4] = {};
  const float* sall = scores + (size_t)bc * 16384;
  for (int ks = 0; ks < 4; ++ks) {
    __syncthreads();
#pragma unroll
    for (int i = 0; i < 8; ++i) {
      int id = tid + i * 128;
      int l = id >> 3, c4 = (id & 7) * 4;
      *(float4*)&sc_s[l][c4] = *(const float4*)&sall[(size_t)l * 128 + ks * 32 + c4];
    }
    __syncthreads();

    bf16x8 bfv;
    {
      int p = lane & 7;
      int sb = (lane >> 4) * 8;
      float4 v0 = *(const float4*)&xdtT[p][ks * 32 + sb];
      float4 v1 = *(const float4*)&xdtT[p][ks * 32 + sb + 4];
      bfv[0] = (bf16_t)v0.x; bfv[1] = (bf16_t)v0.y; bfv[2] = (bf16_t)v0.z; bfv[3] = (bf16_t)v0.w;
      bfv[4] = (bf16_t)v1.x; bfv[5] = (bf16_t)v1.y; bfv[6] = (bf16_t)v1.z; bfv[7] = (bf16_t)v1.w;
    }
#pragma unroll
    for (int mf = 0; mf < 4; ++mf) {
      int lbase = (mf * 2 + wid) * 16;
      if (ks * 32 > lbase + 15) continue;
      int l = lbase + (lane & 15);
      float al = acs_s[l];
      int sb = (lane >> 4) * 8;
      int sg = ks * 32 + sb;
      float4 s0 = *(const float4*)&sc_s[l][sb];
      float4 s1 = *(const float4*)&sc_s[l][sb + 4];
      float4 e0 = *(const float4*)&acs_s[sg];
      float4 e1 = *(const float4*)&acs_s[sg + 4];
      float sv[8] = {s0.x, s0.y, s0.z, s0.w, s1.x, s1.y, s1.z, s1.w};
      float ev[8] = {e0.x, e0.y, e0.z, e0.w, e1.x, e1.y, e1.z, e1.w};
      bf16x8 af;
#pragma unroll
      for (int j = 0; j < 8; ++j) {
        float v = sv[j] * __expf(al - ev[j]);
        af[j] = (bf16_t)((sg + j <= l) ? v : 0.f);
      }
      acc[mf] = __builtin_amdgcn_mfma_f32_16x16x32_bf16(af, bfv, acc[mf], 0, 0, 0);
    }
  }

  // Y_off: acc += (C * eacs) @ pv^T  (K = 64 states, 2 MFMA k-steps)
  __syncthreads();
#pragma unroll
  for (int ks2 = 0; ks2 < 2; ++ks2) {
    int kbase = ks2 * 32 + (lane >> 4) * 8;
    bf16x8 bv;
    {
      int p = lane & 15;
      if (p < 8) {
        float4 v0 = *(const float4*)&pv_s[p * 64 + kbase];
        float4 v1 = *(const float4*)&pv_s[p * 64 + kbase + 4];
        bv[0] = (bf16_t)v0.x; bv[1] = (bf16_t)v0.y; bv[2] = (bf16_t)v0.z; bv[3] = (bf16_t)v0.w;
        bv[4] = (bf16_t)v1.x; bv[5] = (bf16_t)v1.y; bv[6] = (bf16_t)v1.z; bv[7] = (bf16_t)v1.w;
      } else {
        bv = (bf16x8)(bf16_t)0.f;
      }
    }
#pragma unroll
    for (int mf = 0; mf < 4; ++mf) {
      int l = (mf * 2 + wid) * 16 + (lane & 15);
      float el = __expf(acs_s[l]);
      bf16x8 c8 = *(const bf16x8*)&xBC[((size_t)(bc * 128 + l)) * 1664 + 1600 + kbase];
      bf16x8 af;
#pragma unroll
      for (int j = 0; j < 8; ++j) af[j] = (bf16_t)((float)c8[j] * el);
      acc[mf] = __builtin_amdgcn_mfma_f32_16x16x32_bf16(af, bv, acc[mf], 0, 0, 0);
    }
  }

  int p = lane & 15;
  if (p < 8) {
    float Dh = Dvec[h];
    int rg = (lane >> 4) * 4;
#pragma unroll
    for (int mf = 0; mf < 4; ++mf) {
      int lbase = (mf * 2 + wid) * 16;
      float* yp = Y + ((size_t)(bc * 128 + lbase + rg)) * 1536 + h * 8 + p;
#pragma unroll
      for (int rr = 0; rr < 4; ++rr) {
        float xv = (float)xBC[((size_t)(bc * 128 + lbase + rg + rr)) * 1664 + h * 8 + p];
        yp[(size_t)rr * 1536] = acc[mf][rr] + Dh * xv;
      }
    }
  }
}

// ---------- gate with silu(z) + RMSNorm -> y2 bf16 ----------
__global__ __launch_bounds__(256) void gatenorm_kernel(const float* __restrict__ Y,
                                                       const bf16_t* __restrict__ zxb,
                                                       const float* __restrict__ norm_w,
                                                       bf16_t* __restrict__ y2b) {
  int m = blockIdx.x;
  int tid = threadIdx.x;
  const float* yrow = Y + (size_t)m * 1536;
  const bf16_t* zrow = zxb + (size_t)m * 3200;
  float vals[6];
  float ss = 0.f;
#pragma unroll
  for (int r = 0; r < 6; ++r) {
    int i = tid + r * 256;
    float v = yrow[i] * siluf((float)zrow[i]);
    vals[r] = v;
    ss = fmaf(v, v, ss);
  }
#pragma unroll
  for (int off = 32; off > 0; off >>= 1) ss += __shfl_down(ss, off);
  __shared__ float red[4];
  int lane = tid & 63, wid = tid >> 6;
  if (lane == 0) red[wid] = ss;
  __syncthreads();
  float tot = red[0] + red[1] + red[2] + red[3];
  float scale = rsqrtf(tot * (1.f / 1536.f) + 1e-5f);
#pragma unroll
  for (int r = 0; r < 6; ++r) {
    int i = tid + r * 256;
    y2b[(size_t)m * 1536 + i] = (bf16_t)(vals[r] * scale * norm_w[i]);
  }
}

extern "C" void kernel_launch(void* const* d_in, const int* in_sizes, int n_in,
                              void* d_out, int out_size, void* d_ws, size_t ws_size,
                              hipStream_t stream) {
  const float* x = (const float*)d_in[0];
  const float* W_in = (const float*)d_in[1];
  const float* conv_w = (const float*)d_in[2];
  const float* conv_b = (const float*)d_in[3];
  const float* dt_bias = (const float*)d_in[4];
  const float* A_log = (const float*)d_in[5];
  const float* Dvec = (const float*)d_in[6];
  const float* norm_w = (const float*)d_in[7];
  const float* W_out = (const float*)d_in[8];
  float* out = (float*)d_out;
  float* ws = (float*)d_ws;

  bf16_t* ub = (bf16_t*)(ws + OFF_UB);
  bf16_t* Wbi = (bf16_t*)(ws + OFF_WBI);
  bf16_t* Wbo = (bf16_t*)(ws + OFF_WBO);
  bf16_t* zxb = (bf16_t*)(ws + OFF_ZX);
  bf16_t* xBC = (bf16_t*)(ws + OFF_XBC);
  float* dtb = ws + OFF_DT;
  float* Acs = ws + OFF_ACS;
  float* sc = ws + OFF_SC;
  float* st = ws + OFF_ST;
  float* pv = ws + OFF_PV;
  float* Yb = ws + OFF_Y;
  bf16_t* y2b = (bf16_t*)(ws + OFF_Y2B);

  transpose_x_kernel<<<dim3(24, 32, 2), 256, 0, stream>>>(x, ub);
  cvt_bf16_kernel<<<2400, 256, 0, stream>>>(W_in, Wbi, 3200 * 768);
  cvt_bf16_kernel<<<1152, 256, 0, stream>>>(W_out, Wbo, 768 * 1536);
  gemm_mfma_bt<4, 0><<<dim3(25, 16), 256, 0, stream>>>(ub, Wbi, zxb, 768, 3200);
  dtproj_kernel<<<dim3(8, 24, 2), 256, 0, stream>>>(x, W_in, dt_bias, dtb);
  conv_kernel<<<dim3(7, 2048), 128, 0, stream>>>(zxb, conv_w, conv_b, xBC);
  scan_kernel<<<3072, 128, 0, stream>>>(dtb, A_log, Acs);
  scores_kernel<<<16, 256, 0, stream>>>(xBC, sc);
  states_mfma_kernel<<<dim3(12, 16), 256, 0, stream>>>(xBC, dtb, Acs, st);
  recur_kernel<<<384, 512, 0, stream>>>(Acs, st, pv);
  ydiag_off_kernel<<<3072, 128, 0, stream>>>(xBC, dtb, Acs, sc, pv, Dvec, Yb);
  gatenorm_kernel<<<2048, 256, 0, stream>>>(Yb, zxb, norm_w, y2b);
  gemm_mfma_bt<2, 1><<<dim3(6, 32), 256, 0, stream>>>(y2b, Wbo, out, 1536, 0);
}

// Round 6
// 203.085 us; speedup vs baseline: 2.2751x; 1.2691x over previous
//
#include <hip/hip_runtime.h>
#include <cstddef>
#include <cstdint>

// Mamba2 forward. Fused bf16 MFMA GEMMs (in-proj incl. dt tail + W cvt in
// staging; out-proj incl. transposed store), bf16 intermediates.
// B=2 L=1024 DMODEL=768 DINNER=1536 NHEADS=192 P=8 N=64 CONVDIM=1664

typedef __bf16 bf16_t;
typedef bf16_t bf16x2 __attribute__((ext_vector_type(2)));
typedef bf16_t bf16x4 __attribute__((ext_vector_type(4)));
typedef bf16_t bf16x8 __attribute__((ext_vector_type(8)));
typedef float f32x4 __attribute__((ext_vector_type(4)));

// ---------------- ws layout (float units) ----------------
#define OFF_UB   ((size_t)0)                 // 2048*768 bf16
#define OFF_ZX   (OFF_UB  + 786432)          // 2048*3200 bf16
#define OFF_XBC  (OFF_ZX  + 3276800)         // 2048*1664 bf16
#define OFF_DT   (OFF_XBC + 1703936)         // 2*192*1024 f32
#define OFF_ACS  (OFF_DT  + 393216)          // 2*192*8*128 f32
#define OFF_SC   (OFF_ACS + 393216)          // 16*128*128 f32
#define OFF_ST   (OFF_SC  + 262144)          // 16*64*1536 f32 [bc][n][hp]
#define OFF_PV   (OFF_ST  + 1572864)         // 16*1536*64 bf16 [bc][hp][n]
#define OFF_Y    (OFF_PV  + 786432)          // 2048*1536 bf16
#define OFF_Y2B  (OFF_Y   + 1572864)         // 2048*1536 bf16
// end = 12,320,768 floats = 49.3 MB

__device__ __forceinline__ float siluf(float x) { return x / (1.f + __expf(-x)); }

// ---------- transpose x (B,768,1024) -> ub bf16 (B*1024, 768) ----------
__global__ __launch_bounds__(256) void transpose_x_kernel(const float* __restrict__ x,
                                                          bf16_t* __restrict__ ub) {
  __shared__ float tile[32][33];
  int b = blockIdx.z;
  int d0 = blockIdx.x * 32, l0 = blockIdx.y * 32;
  int tx = threadIdx.x & 31, ty = threadIdx.x >> 5;
  for (int r = ty; r < 32; r += 8)
    tile[r][tx] = x[((size_t)(b * 768 + d0 + r)) * 1024 + l0 + tx];
  __syncthreads();
  for (int r = ty; r < 32; r += 8)
    ub[((size_t)(b * 1024 + l0 + r)) * 768 + d0 + tx] = (bf16_t)tile[tx][r];
}

// ---------- fused bf16 MFMA GEMM ----------
// C[M rows][128 cols per tile] = A[M][K](bf16) * B32[N][K](f32, cvt in staging)^T
// MODE 0 (in-proj): cols<3200 -> zxb bf16; cols>=3200 -> h=col-3200 (<192):
//   dtb[(b*192+h)*1024+t] = softplus(C + dt_bias[h])   (f32, transposed store)
//   B rows >= 3392 are zero-padded.
// MODE 1 (out-proj): store f32 transposed to out(B,768,1024).
template <int TMF, int MODE>
__global__ __launch_bounds__(256) void gemm_fused(const bf16_t* __restrict__ A,
                                                  const float* __restrict__ B32,
                                                  void* __restrict__ Cv,
                                                  float* __restrict__ dtb,
                                                  const float* __restrict__ dt_bias,
                                                  int K) {
  constexpr int RB = TMF * 32;
  constexpr int NA = RB / 32;
  __shared__ __align__(16) float smemf[8512];  // staging union epilogue (64x133)
  bf16_t* Asmem = (bf16_t*)smemf;
  bf16_t* Bsmem = Asmem + RB * 64;
  float* eps = smemf;

  int tid = threadIdx.x;
  int wave = tid >> 6, lane = tid & 63;
  int wr = wave >> 1, wc = wave & 1;

  int nwg = gridDim.x * gridDim.y;
  int flat = blockIdx.y * gridDim.x + blockIdx.x;
  int q = nwg >> 3;
  int swz = (flat & 7) * q + (flat >> 3);
  int bx = swz % gridDim.x, by = swz / gridDim.x;
  int m0 = by * RB, n0 = bx * 128;

  const bf16_t* Ag = A + (size_t)m0 * K;

  int aofs[NA]; const bf16_t* agp[NA];
#pragma unroll
  for (int i = 0; i < NA; ++i) {
    int id = i * 256 + tid;
    int r = id >> 3, c = id & 7;
    aofs[i] = r * 128 + ((c ^ (r & 7)) << 4);
    agp[i] = Ag + (size_t)r * K + c * 8;
  }
  int bofs[4]; const float* bgp[4]; bool bval[4];
#pragma unroll
  for (int i = 0; i < 4; ++i) {
    int id = i * 256 + tid;
    int r = id >> 3, c = id & 7;
    bofs[i] = r * 128 + ((c ^ (r & 7)) << 4);
    int grow = n0 + r;
    bval[i] = (MODE == 1) || (grow < 3392);
    bgp[i] = B32 + (size_t)grow * K + c * 8;
  }

  f32x4 acc[TMF][4] = {};
  uint4 areg[NA];
  float4 b0[4], b1[4];
#pragma unroll
  for (int i = 0; i < NA; ++i) areg[i] = *(const uint4*)(agp[i]);
#pragma unroll
  for (int i = 0; i < 4; ++i) {
    if (bval[i]) {
      b0[i] = *(const float4*)(bgp[i]);
      b1[i] = *(const float4*)(bgp[i] + 4);
    } else {
      b0[i] = make_float4(0.f, 0.f, 0.f, 0.f);
      b1[i] = make_float4(0.f, 0.f, 0.f, 0.f);
    }
  }

  for (int k0 = 0; k0 < K; k0 += 64) {
    __syncthreads();
#pragma unroll
    for (int i = 0; i < NA; ++i) *(uint4*)((char*)Asmem + aofs[i]) = areg[i];
#pragma unroll
    for (int i = 0; i < 4; ++i) {
      bf16x8 o = {(bf16_t)b0[i].x, (bf16_t)b0[i].y, (bf16_t)b0[i].z, (bf16_t)b0[i].w,
                  (bf16_t)b1[i].x, (bf16_t)b1[i].y, (bf16_t)b1[i].z, (bf16_t)b1[i].w};
      *(bf16x8*)((char*)Bsmem + bofs[i]) = o;
    }
    __syncthreads();
    if (k0 + 64 < K) {
#pragma unroll
      for (int i = 0; i < NA; ++i) areg[i] = *(const uint4*)(agp[i] + k0 + 64);
#pragma unroll
      for (int i = 0; i < 4; ++i) {
        if (bval[i]) {
          b0[i] = *(const float4*)(bgp[i] + k0 + 64);
          b1[i] = *(const float4*)(bgp[i] + k0 + 68);
        }
      }
    }
#pragma unroll
    for (int half = 0; half < 2; ++half) {
      int kk = half * 32;
      int ca = (kk >> 3) + (lane >> 4);
      bf16x8 af[TMF], bfr[4];
#pragma unroll
      for (int f = 0; f < TMF; ++f) {
        int Ra = wr * (TMF * 16) + f * 16 + (lane & 15);
        af[f] = *(const bf16x8*)((const char*)Asmem + Ra * 128 + ((ca ^ (Ra & 7)) << 4));
      }
#pragma unroll
      for (int f = 0; f < 4; ++f) {
        int Rb = wc * 64 + f * 16 + (lane & 15);
        bfr[f] = *(const bf16x8*)((const char*)Bsmem + Rb * 128 + ((ca ^ (Rb & 7)) << 4));
      }
#pragma unroll
      for (int i = 0; i < TMF; ++i)
#pragma unroll
        for (int j = 0; j < 4; ++j)
          acc[i][j] = __builtin_amdgcn_mfma_f32_16x16x32_bf16(af[i], bfr[j], acc[i][j], 0, 0, 0);
    }
  }

#pragma unroll
  for (int p = 0; p < RB / 64; ++p) {
    __syncthreads();
#pragma unroll
    for (int i = 0; i < TMF; ++i) {
      int rg = wr * (TMF * 16) + i * 16;
      if ((rg >> 6) == p) {
        int rl = (rg & 63) + ((lane >> 4) << 2);
#pragma unroll
        for (int j = 0; j < 4; ++j) {
          int col = wc * 64 + j * 16 + (lane & 15);
#pragma unroll
          for (int rr = 0; rr < 4; ++rr)
            eps[(rl + rr) * 133 + col] = acc[i][j][rr];
        }
      }
    }
    __syncthreads();
    if (MODE == 0) {
      if (n0 < 3200) {
        bf16_t* Cb = (bf16_t*)Cv;
#pragma unroll
        for (int r = 0; r < 8; ++r) {
          int idx = tid + r * 256;
          int row = idx >> 5, c4 = (idx & 31) << 2;
          float4 v = *(const float4*)&eps[row * 133 + c4];
          bf16x4 o = {(bf16_t)v.x, (bf16_t)v.y, (bf16_t)v.z, (bf16_t)v.w};
          *(bf16x4*)&Cb[(size_t)(m0 + p * 64 + row) * 3200 + n0 + c4] = o;
        }
      } else {
        int b = m0 >> 10, t0 = (m0 & 1023) + p * 64;
#pragma unroll
        for (int cg = 0; cg < 8; ++cg) {
          int col = cg * 16 + (tid >> 4);
          int h = n0 + col - 3200;
          if (h < 192) {
            int rr = (tid & 15) * 4;
            float bias = dt_bias[h];
            float vv[4];
#pragma unroll
            for (int k = 0; k < 4; ++k) {
              float v = eps[(rr + k) * 133 + col] + bias;
              vv[k] = (v > 20.f) ? v : log1pf(__expf(v));
            }
            *(float4*)&dtb[((size_t)(b * 192 + h)) * 1024 + t0 + rr] =
                make_float4(vv[0], vv[1], vv[2], vv[3]);
          }
        }
      }
    } else {
      float* Cf = (float*)Cv;
      int b = m0 >> 10, l0 = m0 & 1023;
#pragma unroll
      for (int cg = 0; cg < 8; ++cg) {
        int col = cg * 16 + (tid >> 4);
        int rr = (tid & 15) * 4;
        float4 v = make_float4(eps[(rr + 0) * 133 + col], eps[(rr + 1) * 133 + col],
                               eps[(rr + 2) * 133 + col], eps[(rr + 3) * 133 + col]);
        *(float4*)&Cf[((size_t)(b * 768 + n0 + col)) * 1024 + l0 + p * 64 + rr] = v;
      }
    }
  }
}

// ---------- depthwise causal conv + bias + silu (bf16 in/out, 2ch/thr) ----------
__global__ __launch_bounds__(128) void conv_kernel(const bf16_t* __restrict__ zxb,
                                                   const float* __restrict__ conv_w,
                                                   const float* __restrict__ conv_b,
                                                   bf16_t* __restrict__ xBC) {
  int ch2 = blockIdx.x * 128 + threadIdx.x;
  if (ch2 >= 832) return;
  int ch = ch2 * 2;
  int m = blockIdx.y;
  int b = m >> 10, l = m & 1023;
  float a0 = conv_b[ch], a1 = conv_b[ch + 1];
  const bf16_t* base = zxb + (size_t)b * 1024 * 3200 + 1536 + ch;
#pragma unroll
  for (int j = 0; j < 4; ++j) {
    int tj = l - 3 + j;
    if (tj >= 0) {
      bf16x2 v = *(const bf16x2*)&base[(size_t)tj * 3200];
      a0 = fmaf(conv_w[ch * 4 + j], (float)v[0], a0);
      a1 = fmaf(conv_w[(ch + 1) * 4 + j], (float)v[1], a1);
    }
  }
  bf16x2 o = {(bf16_t)siluf(a0), (bf16_t)siluf(a1)};
  *(bf16x2*)&xBC[(size_t)m * 1664 + ch] = o;
}

// ---------- per-chunk inclusive scan of dA ----------
__global__ __launch_bounds__(128) void scan_kernel(const float* __restrict__ dtb,
                                                   const float* __restrict__ A_log,
                                                   float* __restrict__ Acs) {
  __shared__ float s[128];
  int idx = blockIdx.x;
  int c = idx & 7;
  int bh = idx >> 3;
  int h = bh % 192;
  int l = threadIdx.x;
  float Ah = -__expf(A_log[h]);
  float v = dtb[(size_t)bh * 1024 + c * 128 + l] * Ah;
  s[l] = v;
  __syncthreads();
  for (int off = 1; off < 128; off <<= 1) {
    float add = (l >= off) ? s[l - off] : 0.f;
    __syncthreads();
    s[l] += add;
    __syncthreads();
  }
  Acs[(size_t)idx * 128 + l] = s[l];
}

// ---------- scores[l,s] = sum_n Cm[l,n]*Bm[s,n], per (b,c) ----------
__global__ __launch_bounds__(256) void scores_kernel(const bf16_t* __restrict__ xBC,
                                                     float* __restrict__ scores) {
  __shared__ float Cs[16][128];
  __shared__ float Bs[16][128];
  int bc = blockIdx.x;
  const bf16_t* base = xBC + (size_t)bc * 128 * 1664;
  int tx = threadIdx.x & 15, ty = threadIdx.x >> 4;
  float acc[8][8] = {};
  for (int n0 = 0; n0 < 64; n0 += 16) {
    for (int id = threadIdx.x; id < 2048; id += 256) {
      int lr = id >> 4, nn = id & 15;
      Cs[nn][lr] = (float)base[(size_t)lr * 1664 + 1600 + n0 + nn];
      Bs[nn][lr] = (float)base[(size_t)lr * 1664 + 1536 + n0 + nn];
    }
    __syncthreads();
#pragma unroll
    for (int nn = 0; nn < 16; ++nn) {
      float a[8], bb[8];
#pragma unroll
      for (int i = 0; i < 8; ++i) {
        a[i] = Cs[nn][ty * 8 + i];
        bb[i] = Bs[nn][tx * 8 + i];
      }
#pragma unroll
      for (int i = 0; i < 8; ++i)
#pragma unroll
        for (int j = 0; j < 8; ++j) acc[i][j] = fmaf(a[i], bb[j], acc[i][j]);
    }
    __syncthreads();
  }
  float* srow = scores + (size_t)bc * 16384;
#pragma unroll
  for (int i = 0; i < 8; ++i)
#pragma unroll
    for (int j = 0; j < 8; ++j)
      srow[(size_t)(ty * 8 + i) * 128 + tx * 8 + j] = acc[i][j];
}

// ---------- chunk states via MFMA, per (bc, 16-head tile) ----------
__global__ __launch_bounds__(256) void states_mfma_kernel(
    const bf16_t* __restrict__ xBC, const float* __restrict__ dtb,
    const float* __restrict__ Acs, float* __restrict__ st2) {
  __shared__ bf16_t Asm[64 * 128];
  __shared__ bf16_t Wsm[128 * 128];
  __shared__ float dcoef[16][128];
  int tile = blockIdx.x;
  int bc = blockIdx.y;
  int c = bc & 7, b = bc >> 3;
  int hg0 = tile * 16;
  int tid = threadIdx.x;
  int wave = tid >> 6, lane = tid & 63;

#pragma unroll
  for (int i = 0; i < 8; ++i) {
    int id = tid + i * 256;
    int hh = id >> 7, s = id & 127;
    int h = hg0 + hh;
    const float* ar = Acs + (((size_t)(b * 192 + h)) * 8 + c) * 128;
    float dv = dtb[((size_t)(b * 192 + h)) * 1024 + c * 128 + s];
    dcoef[hh][s] = dv * __expf(ar[127] - ar[s]);
  }
#pragma unroll
  for (int i = 0; i < 32; ++i) {
    int id = tid + i * 256;
    int s = id >> 6, n = id & 63;
    float v = (float)xBC[((size_t)(bc * 128 + s)) * 1664 + 1536 + n];
    int byte = n * 256 + (((s >> 3) ^ (n & 7)) << 4) + (s & 7) * 2;
    *(bf16_t*)((char*)Asm + byte) = (bf16_t)v;
  }
  __syncthreads();
#pragma unroll
  for (int i = 0; i < 64; ++i) {
    int id = tid + i * 256;
    int s = id >> 7, hp = id & 127;
    float v = (float)xBC[((size_t)(bc * 128 + s)) * 1664 + hg0 * 8 + hp] * dcoef[hp >> 3][s];
    int byte = hp * 256 + (((s >> 3) ^ (hp & 7)) << 4) + (s & 7) * 2;
    *(bf16_t*)((char*)Wsm + byte) = (bf16_t)v;
  }
  __syncthreads();

  f32x4 acc[4][2] = {};
#pragma unroll
  for (int ks = 0; ks < 4; ++ks) {
    int cc = ks * 4 + (lane >> 4);
    bf16x8 af[4], bfr[2];
#pragma unroll
    for (int i = 0; i < 4; ++i) {
      int Ra = i * 16 + (lane & 15);
      af[i] = *(const bf16x8*)((const char*)Asm + Ra * 256 + ((cc ^ (Ra & 7)) << 4));
    }
#pragma unroll
    for (int j = 0; j < 2; ++j) {
      int Rb = wave * 32 + j * 16 + (lane & 15);
      bfr[j] = *(const bf16x8*)((const char*)Wsm + Rb * 256 + ((cc ^ (Rb & 7)) << 4));
    }
#pragma unroll
    for (int i = 0; i < 4; ++i)
#pragma unroll
      for (int j = 0; j < 2; ++j)
        acc[i][j] = __builtin_amdgcn_mfma_f32_16x16x32_bf16(af[i], bfr[j], acc[i][j], 0, 0, 0);
  }
#pragma unroll
  for (int i = 0; i < 4; ++i)
#pragma unroll
    for (int j = 0; j < 2; ++j) {
      int n = i * 16 + ((lane >> 4) << 2);
      int col = tile * 128 + wave * 32 + j * 16 + (lane & 15);
      float* sp = st2 + (size_t)bc * 98304 + (size_t)n * 1536 + col;
#pragma unroll
      for (int rr = 0; rr < 4; ++rr) sp[(size_t)rr * 1536] = acc[i][j][rr];
    }
}

// ---------- inter-chunk recurrence; st f32 [bc][n][hp] -> pv bf16 [bc][hp][n] ----------
__global__ __launch_bounds__(512) void recur_kernel(const float* __restrict__ Acs,
                                                    const float* __restrict__ states,
                                                    bf16_t* __restrict__ prev) {
  int bh = blockIdx.x;
  int b = bh / 192, h = bh % 192;
  int tid = threadIdx.x;
  int p = tid >> 6, n = tid & 63;
  float s_run = 0.f;
  for (int c = 0; c < 8; ++c) {
    size_t base = (size_t)(b * 8 + c) * 98304;
    prev[base + (size_t)(h * 8 + p) * 64 + n] = (bf16_t)s_run;
    float dAs = Acs[(((size_t)(b * 192 + h)) * 8 + c) * 128 + 127];
    s_run = s_run * __expf(dAs) + states[base + (size_t)n * 1536 + h * 8 + p];
  }
}

// ---------- Y = Y_diag + Y_off + D*x via MFMA, per (b,c,h), 128 thr ----------
__global__ __launch_bounds__(128) void ydiag_off_kernel(
    const bf16_t* __restrict__ xBC, const float* __restrict__ dtb,
    const float* __restrict__ Acs, const float* __restrict__ scores,
    const bf16_t* __restrict__ pv, const float* __restrict__ Dvec,
    bf16_t* __restrict__ Y) {
  __shared__ float sc_s[128][36];
  __shared__ float xdtT[8][132];
  __shared__ float acs_s[128];
  __shared__ bf16_t pv_s[512];
  int idx = blockIdx.x;
  int h = idx % 192;
  int bc = idx / 192;
  int c = bc & 7, b = bc >> 3;
  int tid = threadIdx.x;
  int lane = tid & 63, wid = tid >> 6;

  acs_s[tid] = Acs[(((size_t)(b * 192 + h)) * 8 + c) * 128 + tid];
  {
    int p = tid & 7, s0 = (tid >> 3) * 8;
    const float* dtr = dtb + ((size_t)(b * 192 + h)) * 1024 + c * 128;
#pragma unroll
    for (int j = 0; j < 8; ++j) {
      int s = s0 + j;
      xdtT[p][s] = (float)xBC[((size_t)(bc * 128 + s)) * 1664 + h * 8 + p] * dtr[s];
    }
  }
  {
    const bf16_t* pb = pv + (size_t)bc * 98304 + (size_t)h * 512;
    *(bf16x4*)&pv_s[tid * 4] = *(const bf16x4*)&pb[tid * 4];
  }

  f32x4 acc[4] = {};
  const float* sall = scores + (size_t)bc * 16384;
  for (int ks = 0; ks < 4; ++ks) {
    __syncthreads();
#pragma unroll
    for (int i = 0; i < 8; ++i) {
      int id = tid + i * 128;
      int l = id >> 3, c4 = (id & 7) * 4;
      *(float4*)&sc_s[l][c4] = *(const float4*)&sall[(size_t)l * 128 + ks * 32 + c4];
    }
    __syncthreads();

    bf16x8 bfv;
    {
      int p = lane & 7;
      int sb = (lane >> 4) * 8;
      float4 v0 = *(const float4*)&xdtT[p][ks * 32 + sb];
      float4 v1 = *(const float4*)&xdtT[p][ks * 32 + sb + 4];
      bfv[0] = (bf16_t)v0.x; bfv[1] = (bf16_t)v0.y; bfv[2] = (bf16_t)v0.z; bfv[3] = (bf16_t)v0.w;
      bfv[4] = (bf16_t)v1.x; bfv[5] = (bf16_t)v1.y; bfv[6] = (bf16_t)v1.z; bfv[7] = (bf16_t)v1.w;
    }
#pragma unroll
    for (int mf = 0; mf < 4; ++mf) {
      int lbase = (mf * 2 + wid) * 16;
      if (ks * 32 > lbase + 15) continue;
      int l = lbase + (lane & 15);
      float al = acs_s[l];
      int sb = (lane >> 4) * 8;
      int sg = ks * 32 + sb;
      float4 s0 = *(const float4*)&sc_s[l][sb];
      float4 s1 = *(const float4*)&sc_s[l][sb + 4];
      float4 e0 = *(const float4*)&acs_s[sg];
      float4 e1 = *(const float4*)&acs_s[sg + 4];
      float sv[8] = {s0.x, s0.y, s0.z, s0.w, s1.x, s1.y, s1.z, s1.w};
      float ev[8] = {e0.x, e0.y, e0.z, e0.w, e1.x, e1.y, e1.z, e1.w};
      bf16x8 af;
#pragma unroll
      for (int j = 0; j < 8; ++j) {
        float v = sv[j] * __expf(al - ev[j]);
        af[j] = (bf16_t)((sg + j <= l) ? v : 0.f);
      }
      acc[mf] = __builtin_amdgcn_mfma_f32_16x16x32_bf16(af, bfv, acc[mf], 0, 0, 0);
    }
  }

  // Y_off: acc += (C * eacs) @ pv^T  (K = 64 states, 2 MFMA k-steps)
  __syncthreads();
#pragma unroll
  for (int ks2 = 0; ks2 < 2; ++ks2) {
    int kbase = ks2 * 32 + (lane >> 4) * 8;
    bf16x8 bv;
    {
      int p = lane & 15;
      if (p < 8) {
        bv = *(const bf16x8*)&pv_s[p * 64 + kbase];
      } else {
        bv = (bf16x8)(bf16_t)0.f;
      }
    }
#pragma unroll
    for (int mf = 0; mf < 4; ++mf) {
      int l = (mf * 2 + wid) * 16 + (lane & 15);
      float el = __expf(acs_s[l]);
      bf16x8 c8 = *(const bf16x8*)&xBC[((size_t)(bc * 128 + l)) * 1664 + 1600 + kbase];
      bf16x8 af;
#pragma unroll
      for (int j = 0; j < 8; ++j) af[j] = (bf16_t)((float)c8[j] * el);
      acc[mf] = __builtin_amdgcn_mfma_f32_16x16x32_bf16(af, bv, acc[mf], 0, 0, 0);
    }
  }

  int p = lane & 15;
  if (p < 8) {
    float Dh = Dvec[h];
    int rg = (lane >> 4) * 4;
#pragma unroll
    for (int mf = 0; mf < 4; ++mf) {
      int lbase = (mf * 2 + wid) * 16;
      bf16_t* yp = Y + ((size_t)(bc * 128 + lbase + rg)) * 1536 + h * 8 + p;
#pragma unroll
      for (int rr = 0; rr < 4; ++rr) {
        float xv = (float)xBC[((size_t)(bc * 128 + lbase + rg + rr)) * 1664 + h * 8 + p];
        yp[(size_t)rr * 1536] = (bf16_t)(acc[mf][rr] + Dh * xv);
      }
    }
  }
}

// ---------- gate with silu(z) + RMSNorm -> y2 bf16 ----------
__global__ __launch_bounds__(256) void gatenorm_kernel(const bf16_t* __restrict__ Yb,
                                                       const bf16_t* __restrict__ zxb,
                                                       const float* __restrict__ norm_w,
                                                       bf16_t* __restrict__ y2b) {
  int m = blockIdx.x;
  int tid = threadIdx.x;
  int base = tid * 6;
  const bf16_t* yrow = Yb + (size_t)m * 1536 + base;
  const bf16_t* zrow = zxb + (size_t)m * 3200 + base;
  float vals[6];
  float ss = 0.f;
#pragma unroll
  for (int j = 0; j < 3; ++j) {
    bf16x2 yv = *(const bf16x2*)&yrow[j * 2];
    bf16x2 zv = *(const bf16x2*)&zrow[j * 2];
    float v0 = (float)yv[0] * siluf((float)zv[0]);
    float v1 = (float)yv[1] * siluf((float)zv[1]);
    vals[j * 2] = v0; vals[j * 2 + 1] = v1;
    ss = fmaf(v0, v0, fmaf(v1, v1, ss));
  }
#pragma unroll
  for (int off = 32; off > 0; off >>= 1) ss += __shfl_down(ss, off);
  __shared__ float red[4];
  int lane = tid & 63, wid = tid >> 6;
  if (lane == 0) red[wid] = ss;
  __syncthreads();
  float tot = red[0] + red[1] + red[2] + red[3];
  float scale = rsqrtf(tot * (1.f / 1536.f) + 1e-5f);
  bf16_t* orow = y2b + (size_t)m * 1536 + base;
#pragma unroll
  for (int j = 0; j < 3; ++j) {
    bf16x2 o = {(bf16_t)(vals[j * 2] * scale * norm_w[base + j * 2]),
                (bf16_t)(vals[j * 2 + 1] * scale * norm_w[base + j * 2 + 1])};
    *(bf16x2*)&orow[j * 2] = o;
  }
}

extern "C" void kernel_launch(void* const* d_in, const int* in_sizes, int n_in,
                              void* d_out, int out_size, void* d_ws, size_t ws_size,
                              hipStream_t stream) {
  const float* x = (const float*)d_in[0];
  const float* W_in = (const float*)d_in[1];
  const float* conv_w = (const float*)d_in[2];
  const float* conv_b = (const float*)d_in[3];
  const float* dt_bias = (const float*)d_in[4];
  const float* A_log = (const float*)d_in[5];
  const float* Dvec = (const float*)d_in[6];
  const float* norm_w = (const float*)d_in[7];
  const float* W_out = (const float*)d_in[8];
  float* out = (float*)d_out;
  float* ws = (float*)d_ws;

  bf16_t* ub = (bf16_t*)(ws + OFF_UB);
  bf16_t* zxb = (bf16_t*)(ws + OFF_ZX);
  bf16_t* xBC = (bf16_t*)(ws + OFF_XBC);
  float* dtb = ws + OFF_DT;
  float* Acs = ws + OFF_ACS;
  float* sc = ws + OFF_SC;
  float* st = ws + OFF_ST;
  bf16_t* pv = (bf16_t*)(ws + OFF_PV);
  bf16_t* Yb = (bf16_t*)(ws + OFF_Y);
  bf16_t* y2b = (bf16_t*)(ws + OFF_Y2B);

  transpose_x_kernel<<<dim3(24, 32, 2), 256, 0, stream>>>(x, ub);
  gemm_fused<4, 0><<<dim3(27, 16), 256, 0, stream>>>(ub, W_in, zxb, dtb, dt_bias, 768);
  conv_kernel<<<dim3(7, 2048), 128, 0, stream>>>(zxb, conv_w, conv_b, xBC);
  scan_kernel<<<3072, 128, 0, stream>>>(dtb, A_log, Acs);
  scores_kernel<<<16, 256, 0, stream>>>(xBC, sc);
  states_mfma_kernel<<<dim3(12, 16), 256, 0, stream>>>(xBC, dtb, Acs, st);
  recur_kernel<<<384, 512, 0, stream>>>(Acs, st, pv);
  ydiag_off_kernel<<<3072, 128, 0, stream>>>(xBC, dtb, Acs, sc, pv, Dvec, Yb);
  gatenorm_kernel<<<2048, 256, 0, stream>>>(Yb, zxb, norm_w, y2b);
  gemm_fused<2, 1><<<dim3(6, 32), 256, 0, stream>>>(y2b, W_out, out, nullptr, nullptr, 1536);
}

// Round 7
// 172.188 us; speedup vs baseline: 2.6833x; 1.1794x over previous
//
#include <hip/hip_runtime.h>
#include <cstddef>
#include <cstdint>

// Mamba2 forward. Fused bf16 MFMA GEMMs (small tiles for occupancy,
// bx-major XCD chunking for W L2-residency), bf16 intermediates.
// B=2 L=1024 DMODEL=768 DINNER=1536 NHEADS=192 P=8 N=64 CONVDIM=1664

typedef __bf16 bf16_t;
typedef bf16_t bf16x2 __attribute__((ext_vector_type(2)));
typedef bf16_t bf16x4 __attribute__((ext_vector_type(4)));
typedef bf16_t bf16x8 __attribute__((ext_vector_type(8)));
typedef float f32x4 __attribute__((ext_vector_type(4)));

// ---------------- ws layout (float units) ----------------
#define OFF_UB   ((size_t)0)                 // 2048*768 bf16
#define OFF_ZX   (OFF_UB  + 786432)          // 2048*3200 bf16
#define OFF_XBC  (OFF_ZX  + 3276800)         // 2048*1664 bf16
#define OFF_DT   (OFF_XBC + 1703936)         // 2*192*1024 f32
#define OFF_ACS  (OFF_DT  + 393216)          // 2*192*8*128 f32
#define OFF_SC   (OFF_ACS + 393216)          // 16*128*128 f32
#define OFF_ST   (OFF_SC  + 262144)          // 16*64*1536 f32 [bc][n][hp]
#define OFF_PV   (OFF_ST  + 1572864)         // 16*1536*64 bf16 [bc][hp][n]
#define OFF_Y    (OFF_PV  + 786432)          // 2048*1536 bf16
#define OFF_Y2B  (OFF_Y   + 1572864)         // 2048*1536 bf16

__device__ __forceinline__ float siluf(float x) { return x / (1.f + __expf(-x)); }

// ---------- transpose x (B,768,1024) -> ub bf16 (B*1024, 768) ----------
__global__ __launch_bounds__(256) void transpose_x_kernel(const float* __restrict__ x,
                                                          bf16_t* __restrict__ ub) {
  __shared__ float tile[32][33];
  int b = blockIdx.z;
  int d0 = blockIdx.x * 32, l0 = blockIdx.y * 32;
  int tx = threadIdx.x & 31, ty = threadIdx.x >> 5;
  for (int r = ty; r < 32; r += 8)
    tile[r][tx] = x[((size_t)(b * 768 + d0 + r)) * 1024 + l0 + tx];
  __syncthreads();
  for (int r = ty; r < 32; r += 8)
    ub[((size_t)(b * 1024 + l0 + r)) * 768 + d0 + tx] = (bf16_t)tile[tx][r];
}

// ---------- fused bf16 MFMA GEMM ----------
// C[RB rows][128 cols/tile] = A[M][K](bf16) @ B32[N][K](f32, cvt in staging)^T
// MODE 0 (in-proj): cols<3200 -> zxb bf16; cols>=3200 -> h=col-3200 (<192):
//   dtb[(b*192+h)*1024+t] = softplus(C + dt_bias[h]) (f32, t-contig store);
//   B rows >= 3392 zero-padded.
// MODE 1 (out-proj): store f32 transposed to out(B,768,1024).
// Grid (n-tiles, m-tiles); bx-major XCD chunking keeps each XCD's W slice
// L2-resident. Epilogue staged in 32-row LDS slabs (keeps LDS small).
template <int TMF, int MODE>
__global__ __launch_bounds__(256) void gemm_fused(const bf16_t* __restrict__ A,
                                                  const float* __restrict__ B32,
                                                  void* __restrict__ Cv,
                                                  float* __restrict__ dtb,
                                                  const float* __restrict__ dt_bias,
                                                  int K) {
  constexpr int RB = TMF * 32;
  constexpr int NA = RB / 32;
  constexpr int STG = (RB * 64 + 128 * 64) / 2;       // staging floats
  constexpr int SMEMN = (STG > 4256) ? STG : 4256;    // union w/ 32x133 epilogue
  __shared__ __align__(16) float smemf[SMEMN];
  bf16_t* Asmem = (bf16_t*)smemf;
  bf16_t* Bsmem = Asmem + RB * 64;
  float* eps = smemf;

  int tid = threadIdx.x;
  int wave = tid >> 6, lane = tid & 63;
  int wr = wave >> 1, wc = wave & 1;

  // bx-major XCD chunking: each XCD gets contiguous column-major range.
  int gx = gridDim.x, gy = gridDim.y;
  int nwg = gx * gy;
  int flat = blockIdx.y * gx + blockIdx.x;
  int q = nwg >> 3;
  int cm = (flat & 7) * q + (flat >> 3);
  int bx = cm / gy, by = cm % gy;
  int m0 = by * RB, n0 = bx * 128;

  const bf16_t* Ag = A + (size_t)m0 * K;

  int aofs[NA]; const bf16_t* agp[NA];
#pragma unroll
  for (int i = 0; i < NA; ++i) {
    int id = i * 256 + tid;
    int r = id >> 3, c = id & 7;
    aofs[i] = r * 128 + ((c ^ (r & 7)) << 4);
    agp[i] = Ag + (size_t)r * K + c * 8;
  }
  int bofs[4]; const float* bgp[4]; bool bval[4];
#pragma unroll
  for (int i = 0; i < 4; ++i) {
    int id = i * 256 + tid;
    int r = id >> 3, c = id & 7;
    bofs[i] = r * 128 + ((c ^ (r & 7)) << 4);
    int grow = n0 + r;
    bval[i] = (MODE == 1) || (grow < 3392);
    bgp[i] = B32 + (size_t)grow * K + c * 8;
  }

  f32x4 acc[TMF][4] = {};
  uint4 areg[NA];
  float4 b0[4], b1[4];
#pragma unroll
  for (int i = 0; i < NA; ++i) areg[i] = *(const uint4*)(agp[i]);
#pragma unroll
  for (int i = 0; i < 4; ++i) {
    if (bval[i]) {
      b0[i] = *(const float4*)(bgp[i]);
      b1[i] = *(const float4*)(bgp[i] + 4);
    } else {
      b0[i] = make_float4(0.f, 0.f, 0.f, 0.f);
      b1[i] = make_float4(0.f, 0.f, 0.f, 0.f);
    }
  }

  for (int k0 = 0; k0 < K; k0 += 64) {
    __syncthreads();
#pragma unroll
    for (int i = 0; i < NA; ++i) *(uint4*)((char*)Asmem + aofs[i]) = areg[i];
#pragma unroll
    for (int i = 0; i < 4; ++i) {
      bf16x8 o = {(bf16_t)b0[i].x, (bf16_t)b0[i].y, (bf16_t)b0[i].z, (bf16_t)b0[i].w,
                  (bf16_t)b1[i].x, (bf16_t)b1[i].y, (bf16_t)b1[i].z, (bf16_t)b1[i].w};
      *(bf16x8*)((char*)Bsmem + bofs[i]) = o;
    }
    __syncthreads();
    if (k0 + 64 < K) {
#pragma unroll
      for (int i = 0; i < NA; ++i) areg[i] = *(const uint4*)(agp[i] + k0 + 64);
#pragma unroll
      for (int i = 0; i < 4; ++i) {
        if (bval[i]) {
          b0[i] = *(const float4*)(bgp[i] + k0 + 64);
          b1[i] = *(const float4*)(bgp[i] + k0 + 68);
        }
      }
    }
#pragma unroll
    for (int half = 0; half < 2; ++half) {
      int kk = half * 32;
      int ca = (kk >> 3) + (lane >> 4);
      bf16x8 af[TMF], bfr[4];
#pragma unroll
      for (int f = 0; f < TMF; ++f) {
        int Ra = wr * (TMF * 16) + f * 16 + (lane & 15);
        af[f] = *(const bf16x8*)((const char*)Asmem + Ra * 128 + ((ca ^ (Ra & 7)) << 4));
      }
#pragma unroll
      for (int f = 0; f < 4; ++f) {
        int Rb = wc * 64 + f * 16 + (lane & 15);
        bfr[f] = *(const bf16x8*)((const char*)Bsmem + Rb * 128 + ((ca ^ (Rb & 7)) << 4));
      }
#pragma unroll
      for (int i = 0; i < TMF; ++i)
#pragma unroll
        for (int j = 0; j < 4; ++j)
          acc[i][j] = __builtin_amdgcn_mfma_f32_16x16x32_bf16(af[i], bfr[j], acc[i][j], 0, 0, 0);
    }
  }

  // Epilogue: 32-row LDS slabs -> coalesced stores.
#pragma unroll
  for (int p = 0; p < RB / 32; ++p) {
    __syncthreads();
#pragma unroll
    for (int i = 0; i < TMF; ++i) {
      int rg = wr * (TMF * 16) + i * 16;
      if ((rg >> 5) == p) {
        int rl = (rg & 31) + ((lane >> 4) << 2);
#pragma unroll
        for (int j = 0; j < 4; ++j) {
          int col = wc * 64 + j * 16 + (lane & 15);
#pragma unroll
          for (int rr = 0; rr < 4; ++rr)
            eps[(rl + rr) * 133 + col] = acc[i][j][rr];
        }
      }
    }
    __syncthreads();
    if (MODE == 0) {
      if (n0 < 3200) {
        bf16_t* Cb = (bf16_t*)Cv;
#pragma unroll
        for (int r = 0; r < 4; ++r) {
          int idx = tid + r * 256;
          int row = idx >> 5, c4 = (idx & 31) << 2;
          float4 v = *(const float4*)&eps[row * 133 + c4];
          bf16x4 o = {(bf16_t)v.x, (bf16_t)v.y, (bf16_t)v.z, (bf16_t)v.w};
          *(bf16x4*)&Cb[(size_t)(m0 + p * 32 + row) * 3200 + n0 + c4] = o;
        }
      } else {
        int b = m0 >> 10, t0 = (m0 & 1023) + p * 32;
#pragma unroll
        for (int cg = 0; cg < 4; ++cg) {
          int col = cg * 32 + (tid >> 3);
          int h = n0 + col - 3200;
          if (h < 192) {
            int rr = (tid & 7) * 4;
            float bias = dt_bias[h];
            float vv[4];
#pragma unroll
            for (int k = 0; k < 4; ++k) {
              float v = eps[(rr + k) * 133 + col] + bias;
              vv[k] = (v > 20.f) ? v : log1pf(__expf(v));
            }
            *(float4*)&dtb[((size_t)(b * 192 + h)) * 1024 + t0 + rr] =
                make_float4(vv[0], vv[1], vv[2], vv[3]);
          }
        }
      }
    } else {
      float* Cf = (float*)Cv;
      int b = m0 >> 10, l0 = (m0 & 1023) + p * 32;
#pragma unroll
      for (int cg = 0; cg < 4; ++cg) {
        int col = cg * 32 + (tid >> 3);
        int rr = (tid & 7) * 4;
        float4 v = make_float4(eps[(rr + 0) * 133 + col], eps[(rr + 1) * 133 + col],
                               eps[(rr + 2) * 133 + col], eps[(rr + 3) * 133 + col]);
        *(float4*)&Cf[((size_t)(b * 768 + n0 + col)) * 1024 + l0 + rr] = v;
      }
    }
  }
}

// ---------- depthwise causal conv + bias + silu (bf16 in/out, 2ch/thr) ----------
__global__ __launch_bounds__(128) void conv_kernel(const bf16_t* __restrict__ zxb,
                                                   const float* __restrict__ conv_w,
                                                   const float* __restrict__ conv_b,
                                                   bf16_t* __restrict__ xBC) {
  int ch2 = blockIdx.x * 128 + threadIdx.x;
  if (ch2 >= 832) return;
  int ch = ch2 * 2;
  int m = blockIdx.y;
  int b = m >> 10, l = m & 1023;
  float a0 = conv_b[ch], a1 = conv_b[ch + 1];
  const bf16_t* base = zxb + (size_t)b * 1024 * 3200 + 1536 + ch;
#pragma unroll
  for (int j = 0; j < 4; ++j) {
    int tj = l - 3 + j;
    if (tj >= 0) {
      bf16x2 v = *(const bf16x2*)&base[(size_t)tj * 3200];
      a0 = fmaf(conv_w[ch * 4 + j], (float)v[0], a0);
      a1 = fmaf(conv_w[(ch + 1) * 4 + j], (float)v[1], a1);
    }
  }
  bf16x2 o = {(bf16_t)siluf(a0), (bf16_t)siluf(a1)};
  *(bf16x2*)&xBC[(size_t)m * 1664 + ch] = o;
}

// ---------- per-chunk inclusive scan of dA ----------
__global__ __launch_bounds__(128) void scan_kernel(const float* __restrict__ dtb,
                                                   const float* __restrict__ A_log,
                                                   float* __restrict__ Acs) {
  __shared__ float s[128];
  int idx = blockIdx.x;
  int c = idx & 7;
  int bh = idx >> 3;
  int h = bh % 192;
  int l = threadIdx.x;
  float Ah = -__expf(A_log[h]);
  float v = dtb[(size_t)bh * 1024 + c * 128 + l] * Ah;
  s[l] = v;
  __syncthreads();
  for (int off = 1; off < 128; off <<= 1) {
    float add = (l >= off) ? s[l - off] : 0.f;
    __syncthreads();
    s[l] += add;
    __syncthreads();
  }
  Acs[(size_t)idx * 128 + l] = s[l];
}

// ---------- scores[l,s] = sum_n Cm[l,n]*Bm[s,n]; grid (bc, 8 l-slabs) ----------
__global__ __launch_bounds__(256) void scores_kernel(const bf16_t* __restrict__ xBC,
                                                     float* __restrict__ scores) {
  __shared__ float Cs[16][16];
  __shared__ float Bs[16][128];
  int bc = blockIdx.x;
  int l0 = blockIdx.y * 16;
  const bf16_t* base = xBC + (size_t)bc * 128 * 1664;
  int tid = threadIdx.x;
  int tx = tid & 15, ty = tid >> 4;
  float acc[8] = {};
  for (int n0 = 0; n0 < 64; n0 += 16) {
    Cs[tid & 15][tid >> 4] =
        (float)base[(size_t)(l0 + (tid >> 4)) * 1664 + 1600 + n0 + (tid & 15)];
    for (int id = tid; id < 2048; id += 256) {
      int sr = id >> 4, nn = id & 15;
      Bs[nn][sr] = (float)base[(size_t)sr * 1664 + 1536 + n0 + nn];
    }
    __syncthreads();
#pragma unroll
    for (int nn = 0; nn < 16; ++nn) {
      float a = Cs[nn][ty];
#pragma unroll
      for (int j = 0; j < 8; ++j)
        acc[j] = fmaf(a, Bs[nn][tx * 8 + j], acc[j]);
    }
    __syncthreads();
  }
  float* srow = scores + (size_t)bc * 16384 + (size_t)(l0 + ty) * 128;
#pragma unroll
  for (int j = 0; j < 8; ++j) srow[tx * 8 + j] = acc[j];
}

// ---------- chunk states via MFMA, per (bc, 16-head tile) ----------
__global__ __launch_bounds__(256) void states_mfma_kernel(
    const bf16_t* __restrict__ xBC, const float* __restrict__ dtb,
    const float* __restrict__ Acs, float* __restrict__ st2) {
  __shared__ bf16_t Asm[64 * 128];
  __shared__ bf16_t Wsm[128 * 128];
  __shared__ float dcoef[16][128];
  int tile = blockIdx.x;
  int bc = blockIdx.y;
  int c = bc & 7, b = bc >> 3;
  int hg0 = tile * 16;
  int tid = threadIdx.x;
  int wave = tid >> 6, lane = tid & 63;

#pragma unroll
  for (int i = 0; i < 8; ++i) {
    int id = tid + i * 256;
    int hh = id >> 7, s = id & 127;
    int h = hg0 + hh;
    const float* ar = Acs + (((size_t)(b * 192 + h)) * 8 + c) * 128;
    float dv = dtb[((size_t)(b * 192 + h)) * 1024 + c * 128 + s];
    dcoef[hh][s] = dv * __expf(ar[127] - ar[s]);
  }
#pragma unroll
  for (int i = 0; i < 32; ++i) {
    int id = tid + i * 256;
    int s = id >> 6, n = id & 63;
    float v = (float)xBC[((size_t)(bc * 128 + s)) * 1664 + 1536 + n];
    int byte = n * 256 + (((s >> 3) ^ (n & 7)) << 4) + (s & 7) * 2;
    *(bf16_t*)((char*)Asm + byte) = (bf16_t)v;
  }
  __syncthreads();
#pragma unroll
  for (int i = 0; i < 64; ++i) {
    int id = tid + i * 256;
    int s = id >> 7, hp = id & 127;
    float v = (float)xBC[((size_t)(bc * 128 + s)) * 1664 + hg0 * 8 + hp] * dcoef[hp >> 3][s];
    int byte = hp * 256 + (((s >> 3) ^ (hp & 7)) << 4) + (s & 7) * 2;
    *(bf16_t*)((char*)Wsm + byte) = (bf16_t)v;
  }
  __syncthreads();

  f32x4 acc[4][2] = {};
#pragma unroll
  for (int ks = 0; ks < 4; ++ks) {
    int cc = ks * 4 + (lane >> 4);
    bf16x8 af[4], bfr[2];
#pragma unroll
    for (int i = 0; i < 4; ++i) {
      int Ra = i * 16 + (lane & 15);
      af[i] = *(const bf16x8*)((const char*)Asm + Ra * 256 + ((cc ^ (Ra & 7)) << 4));
    }
#pragma unroll
    for (int j = 0; j < 2; ++j) {
      int Rb = wave * 32 + j * 16 + (lane & 15);
      bfr[j] = *(const bf16x8*)((const char*)Wsm + Rb * 256 + ((cc ^ (Rb & 7)) << 4));
    }
#pragma unroll
    for (int i = 0; i < 4; ++i)
#pragma unroll
      for (int j = 0; j < 2; ++j)
        acc[i][j] = __builtin_amdgcn_mfma_f32_16x16x32_bf16(af[i], bfr[j], acc[i][j], 0, 0, 0);
  }
#pragma unroll
  for (int i = 0; i < 4; ++i)
#pragma unroll
    for (int j = 0; j < 2; ++j) {
      int n = i * 16 + ((lane >> 4) << 2);
      int col = tile * 128 + wave * 32 + j * 16 + (lane & 15);
      float* sp = st2 + (size_t)bc * 98304 + (size_t)n * 1536 + col;
#pragma unroll
      for (int rr = 0; rr < 4; ++rr) sp[(size_t)rr * 1536] = acc[i][j][rr];
    }
}

// ---------- inter-chunk recurrence; st f32 [bc][n][hp] -> pv bf16 [bc][hp][n] ----------
__global__ __launch_bounds__(512) void recur_kernel(const float* __restrict__ Acs,
                                                    const float* __restrict__ states,
                                                    bf16_t* __restrict__ prev) {
  int bh = blockIdx.x;
  int b = bh / 192, h = bh % 192;
  int tid = threadIdx.x;
  int p = tid >> 6, n = tid & 63;
  float s_run = 0.f;
  for (int c = 0; c < 8; ++c) {
    size_t base = (size_t)(b * 8 + c) * 98304;
    prev[base + (size_t)(h * 8 + p) * 64 + n] = (bf16_t)s_run;
    float dAs = Acs[(((size_t)(b * 192 + h)) * 8 + c) * 128 + 127];
    s_run = s_run * __expf(dAs) + states[base + (size_t)n * 1536 + h * 8 + p];
  }
}

// ---------- Y = Y_diag + Y_off + D*x via MFMA, per (b,c,h), 128 thr ----------
__global__ __launch_bounds__(128) void ydiag_off_kernel(
    const bf16_t* __restrict__ xBC, const float* __restrict__ dtb,
    const float* __restrict__ Acs, const float* __restrict__ scores,
    const bf16_t* __restrict__ pv, const float* __restrict__ Dvec,
    bf16_t* __restrict__ Y) {
  __shared__ float sc_s[128][36];
  __shared__ float xdtT[8][132];
  __shared__ float acs_s[128];
  __shared__ bf16_t pv_s[512];
  int idx = blockIdx.x;
  int h = idx % 192;
  int bc = idx / 192;
  int c = bc & 7, b = bc >> 3;
  int tid = threadIdx.x;
  int lane = tid & 63, wid = tid >> 6;

  acs_s[tid] = Acs[(((size_t)(b * 192 + h)) * 8 + c) * 128 + tid];
  {
    int p = tid & 7, s0 = (tid >> 3) * 8;
    const float* dtr = dtb + ((size_t)(b * 192 + h)) * 1024 + c * 128;
#pragma unroll
    for (int j = 0; j < 8; ++j) {
      int s = s0 + j;
      xdtT[p][s] = (float)xBC[((size_t)(bc * 128 + s)) * 1664 + h * 8 + p] * dtr[s];
    }
  }
  {
    const bf16_t* pb = pv + (size_t)bc * 98304 + (size_t)h * 512;
    *(bf16x4*)&pv_s[tid * 4] = *(const bf16x4*)&pb[tid * 4];
  }

  f32x4 acc[4] = {};
  const float* sall = scores + (size_t)bc * 16384;
  for (int ks = 0; ks < 4; ++ks) {
    __syncthreads();
#pragma unroll
    for (int i = 0; i < 8; ++i) {
      int id = tid + i * 128;
      int l = id >> 3, c4 = (id & 7) * 4;
      *(float4*)&sc_s[l][c4] = *(const float4*)&sall[(size_t)l * 128 + ks * 32 + c4];
    }
    __syncthreads();

    bf16x8 bfv;
    {
      int p = lane & 7;
      int sb = (lane >> 4) * 8;
      float4 v0 = *(const float4*)&xdtT[p][ks * 32 + sb];
      float4 v1 = *(const float4*)&xdtT[p][ks * 32 + sb + 4];
      bfv[0] = (bf16_t)v0.x; bfv[1] = (bf16_t)v0.y; bfv[2] = (bf16_t)v0.z; bfv[3] = (bf16_t)v0.w;
      bfv[4] = (bf16_t)v1.x; bfv[5] = (bf16_t)v1.y; bfv[6] = (bf16_t)v1.z; bfv[7] = (bf16_t)v1.w;
    }
#pragma unroll
    for (int mf = 0; mf < 4; ++mf) {
      int lbase = (mf * 2 + wid) * 16;
      if (ks * 32 > lbase + 15) continue;
      int l = lbase + (lane & 15);
      float al = acs_s[l];
      int sb = (lane >> 4) * 8;
      int sg = ks * 32 + sb;
      float4 s0 = *(const float4*)&sc_s[l][sb];
      float4 s1 = *(const float4*)&sc_s[l][sb + 4];
      float4 e0 = *(const float4*)&acs_s[sg];
      float4 e1 = *(const float4*)&acs_s[sg + 4];
      float sv[8] = {s0.x, s0.y, s0.z, s0.w, s1.x, s1.y, s1.z, s1.w};
      float ev[8] = {e0.x, e0.y, e0.z, e0.w, e1.x, e1.y, e1.z, e1.w};
      bf16x8 af;
#pragma unroll
      for (int j = 0; j < 8; ++j) {
        float v = sv[j] * __expf(al - ev[j]);
        af[j] = (bf16_t)((sg + j <= l) ? v : 0.f);
      }
      acc[mf] = __builtin_amdgcn_mfma_f32_16x16x32_bf16(af, bfv, acc[mf], 0, 0, 0);
    }
  }

  // Y_off: acc += (C * eacs) @ pv^T  (K = 64 states, 2 MFMA k-steps)
  __syncthreads();
#pragma unroll
  for (int ks2 = 0; ks2 < 2; ++ks2) {
    int kbase = ks2 * 32 + (lane >> 4) * 8;
    bf16x8 bv;
    {
      int p = lane & 15;
      if (p < 8) {
        bv = *(const bf16x8*)&pv_s[p * 64 + kbase];
      } else {
        bv = (bf16x8)(bf16_t)0.f;
      }
    }
#pragma unroll
    for (int mf = 0; mf < 4; ++mf) {
      int l = (mf * 2 + wid) * 16 + (lane & 15);
      float el = __expf(acs_s[l]);
      bf16x8 c8 = *(const bf16x8*)&xBC[((size_t)(bc * 128 + l)) * 1664 + 1600 + kbase];
      bf16x8 af;
#pragma unroll
      for (int j = 0; j < 8; ++j) af[j] = (bf16_t)((float)c8[j] * el);
      acc[mf] = __builtin_amdgcn_mfma_f32_16x16x32_bf16(af, bv, acc[mf], 0, 0, 0);
    }
  }

  int p = lane & 15;
  if (p < 8) {
    float Dh = Dvec[h];
    int rg = (lane >> 4) * 4;
#pragma unroll
    for (int mf = 0; mf < 4; ++mf) {
      int lbase = (mf * 2 + wid) * 16;
      bf16_t* yp = Y + ((size_t)(bc * 128 + lbase + rg)) * 1536 + h * 8 + p;
#pragma unroll
      for (int rr = 0; rr < 4; ++rr) {
        float xv = (float)xBC[((size_t)(bc * 128 + lbase + rg + rr)) * 1664 + h * 8 + p];
        yp[(size_t)rr * 1536] = (bf16_t)(acc[mf][rr] + Dh * xv);
      }
    }
  }
}

// ---------- gate with silu(z) + RMSNorm -> y2 bf16 ----------
__global__ __launch_bounds__(256) void gatenorm_kernel(const bf16_t* __restrict__ Yb,
                                                       const bf16_t* __restrict__ zxb,
                                                       const float* __restrict__ norm_w,
                                                       bf16_t* __restrict__ y2b) {
  int m = blockIdx.x;
  int tid = threadIdx.x;
  int base = tid * 6;
  const bf16_t* yrow = Yb + (size_t)m * 1536 + base;
  const bf16_t* zrow = zxb + (size_t)m * 3200 + base;
  float vals[6];
  float ss = 0.f;
#pragma unroll
  for (int j = 0; j < 3; ++j) {
    bf16x2 yv = *(const bf16x2*)&yrow[j * 2];
    bf16x2 zv = *(const bf16x2*)&zrow[j * 2];
    float v0 = (float)yv[0] * siluf((float)zv[0]);
    float v1 = (float)yv[1] * siluf((float)zv[1]);
    vals[j * 2] = v0; vals[j * 2 + 1] = v1;
    ss = fmaf(v0, v0, fmaf(v1, v1, ss));
  }
#pragma unroll
  for (int off = 32; off > 0; off >>= 1) ss += __shfl_down(ss, off);
  __shared__ float red[4];
  int lane = tid & 63, wid = tid >> 6;
  if (lane == 0) red[wid] = ss;
  __syncthreads();
  float tot = red[0] + red[1] + red[2] + red[3];
  float scale = rsqrtf(tot * (1.f / 1536.f) + 1e-5f);
  bf16_t* orow = y2b + (size_t)m * 1536 + base;
#pragma unroll
  for (int j = 0; j < 3; ++j) {
    bf16x2 o = {(bf16_t)(vals[j * 2] * scale * norm_w[base + j * 2]),
                (bf16_t)(vals[j * 2 + 1] * scale * norm_w[base + j * 2 + 1])};
    *(bf16x2*)&orow[j * 2] = o;
  }
}

extern "C" void kernel_launch(void* const* d_in, const int* in_sizes, int n_in,
                              void* d_out, int out_size, void* d_ws, size_t ws_size,
                              hipStream_t stream) {
  const float* x = (const float*)d_in[0];
  const float* W_in = (const float*)d_in[1];
  const float* conv_w = (const float*)d_in[2];
  const float* conv_b = (const float*)d_in[3];
  const float* dt_bias = (const float*)d_in[4];
  const float* A_log = (const float*)d_in[5];
  const float* Dvec = (const float*)d_in[6];
  const float* norm_w = (const float*)d_in[7];
  const float* W_out = (const float*)d_in[8];
  float* out = (float*)d_out;
  float* ws = (float*)d_ws;

  bf16_t* ub = (bf16_t*)(ws + OFF_UB);
  bf16_t* zxb = (bf16_t*)(ws + OFF_ZX);
  bf16_t* xBC = (bf16_t*)(ws + OFF_XBC);
  float* dtb = ws + OFF_DT;
  float* Acs = ws + OFF_ACS;
  float* sc = ws + OFF_SC;
  float* st = ws + OFF_ST;
  bf16_t* pv = (bf16_t*)(ws + OFF_PV);
  bf16_t* Yb = (bf16_t*)(ws + OFF_Y);
  bf16_t* y2b = (bf16_t*)(ws + OFF_Y2B);

  transpose_x_kernel<<<dim3(24, 32, 2), 256, 0, stream>>>(x, ub);
  gemm_fused<2, 0><<<dim3(27, 32), 256, 0, stream>>>(ub, W_in, zxb, dtb, dt_bias, 768);
  conv_kernel<<<dim3(7, 2048), 128, 0, stream>>>(zxb, conv_w, conv_b, xBC);
  scan_kernel<<<3072, 128, 0, stream>>>(dtb, A_log, Acs);
  scores_kernel<<<dim3(16, 8), 256, 0, stream>>>(xBC, sc);
  states_mfma_kernel<<<dim3(12, 16), 256, 0, stream>>>(xBC, dtb, Acs, st);
  recur_kernel<<<384, 512, 0, stream>>>(Acs, st, pv);
  ydiag_off_kernel<<<3072, 128, 0, stream>>>(xBC, dtb, Acs, sc, pv, Dvec, Yb);
  gatenorm_kernel<<<2048, 256, 0, stream>>>(Yb, zxb, norm_w, y2b);
  gemm_fused<1, 1><<<dim3(6, 64), 256, 0, stream>>>(y2b, W_out, out, nullptr, nullptr, 1536);
}